// Round 7
// baseline (907.960 us; speedup 1.0000x reference)
//
#include <hip/hip_runtime.h>
#include <hip/hip_bf16.h>

// Problem constants (from reference)
#define NN 50000
#define EE 800000
#define GG 64
#define RR 3
#define CC 10
// Y layout per node (832 cols): [0:128 fs | 128:192 xs | 192:384 xr(r=0..2) |
//                                384:768 fm(r, beta|gamma) | 768:832 xp]
// post_k: col 0:64 <- skip_out; col 64:128 <- 0 (agg accum); col 128:192 <- 0
// (S accum); builds XG bf16 [xp|xr0|xr1|xr2]; m[n] <- self energy.
// edge8_k: atomicAdd into Y cols 64:192. feats_k: feats -> cols 192:320.

__device__ inline float leaky02(float x) { return x > 0.f ? x : 0.2f * x; }

__device__ inline void atomicMaxF(float* addr, float v) {
  if (v >= 0.f) atomicMax((int*)addr, __float_as_int(v));
  else          atomicMin((unsigned int*)addr, __float_as_uint(v));
}

// valid for non-negative floats only
__device__ inline void atomicMaxFPos(float* addr, float v) {
  atomicMax((int*)addr, __float_as_int(v));
}

// ---- pack node weights into Wcat (64 x 832) + bias vec (832) ------------
__global__ void pack_w_k(const float* __restrict__ skip_film_W,
                         const float* __restrict__ skip_W,
                         const float* __restrict__ film_lin_W,
                         const float* __restrict__ film_film_W,
                         const float* __restrict__ gat_W,
                         const float* __restrict__ skip_film_b,
                         const float* __restrict__ film_film_b,
                         float* __restrict__ Wcat, float* __restrict__ bias) {
  int idx = blockIdx.x * blockDim.x + threadIdx.x;
  if (idx >= 64 * 832 + 832) return;
  if (idx >= 64 * 832) {
    int c = idx - 64 * 832;
    float b = 0.f;
    if (c < 128) b = skip_film_b[c];
    else if (c >= 384 && c < 768) b = film_film_b[c - 384];
    bias[c] = b;
    return;
  }
  int k = idx / 832, c = idx % 832;
  float v;
  if (c < 128)      v = skip_film_W[k * 128 + c];
  else if (c < 192) v = skip_W[k * 64 + (c - 128)];
  else if (c < 384) { int cc = c - 192, r = cc >> 6, h = cc & 63;
                      v = film_lin_W[(r * 64 + k) * 64 + h]; }
  else if (c < 768) { int cc = c - 384, r = cc >> 7, j = cc & 127;
                      v = film_film_W[(r * 64 + k) * 128 + j]; }
  else              v = gat_W[k * 64 + (c - 768)];
  Wcat[idx] = v;
}

// ---- X(50000x64) @ Wcat(64x832) + bias -> Y -----------------------------
__global__ __launch_bounds__(256) void gemm_k(const float* __restrict__ X,
                                              const float* __restrict__ W,
                                              const float* __restrict__ bias,
                                              float* __restrict__ Y) {
  __shared__ __align__(16) float As[64][65];
  __shared__ __align__(16) float Bs[64][128];
  const int tid = threadIdx.x;
  const int row0 = blockIdx.x * 64;
  const int col0 = blockIdx.y * 128;

  #pragma unroll
  for (int s = 0; s < 4; s++) {
    int q = s * 256 + tid;
    int r = q >> 4;
    int c4 = (q & 15) << 2;
    int gr = row0 + r;
    float4 v = make_float4(0.f, 0.f, 0.f, 0.f);
    if (gr < NN) v = *reinterpret_cast<const float4*>(X + (size_t)gr * 64 + c4);
    As[r][c4 + 0] = v.x; As[r][c4 + 1] = v.y;
    As[r][c4 + 2] = v.z; As[r][c4 + 3] = v.w;
  }
  #pragma unroll
  for (int s = 0; s < 8; s++) {
    int q = s * 256 + tid;
    int r = q >> 5;
    int c4 = (q & 31) << 2;
    int gc = col0 + c4;
    float4 v = make_float4(0.f, 0.f, 0.f, 0.f);
    if (gc + 3 < 832) v = *reinterpret_cast<const float4*>(W + (size_t)r * 832 + gc);
    *reinterpret_cast<float4*>(&Bs[r][c4]) = v;
  }
  __syncthreads();

  const int tx = tid & 15, ty = tid >> 4;
  float acc[4][8] = {};
  #pragma unroll 8
  for (int k = 0; k < 64; k++) {
    float a0 = As[ty * 4 + 0][k], a1 = As[ty * 4 + 1][k];
    float a2 = As[ty * 4 + 2][k], a3 = As[ty * 4 + 3][k];
    const float4* bp = reinterpret_cast<const float4*>(&Bs[k][tx * 8]);
    float4 b0 = bp[0], b1 = bp[1];
    float bb[8] = {b0.x, b0.y, b0.z, b0.w, b1.x, b1.y, b1.z, b1.w};
    #pragma unroll
    for (int j = 0; j < 8; j++) {
      acc[0][j] += a0 * bb[j]; acc[1][j] += a1 * bb[j];
      acc[2][j] += a2 * bb[j]; acc[3][j] += a3 * bb[j];
    }
  }
  int gc = col0 + tx * 8;
  if (gc + 7 < 832) {
    float4 bv0 = *reinterpret_cast<const float4*>(bias + gc);
    float4 bv1 = *reinterpret_cast<const float4*>(bias + gc + 4);
    #pragma unroll
    for (int i = 0; i < 4; i++) {
      int gr = row0 + ty * 4 + i;
      if (gr >= NN) continue;
      float4 o0 = {acc[i][0] + bv0.x, acc[i][1] + bv0.y,
                   acc[i][2] + bv0.z, acc[i][3] + bv0.w};
      float4 o1 = {acc[i][4] + bv1.x, acc[i][5] + bv1.y,
                   acc[i][6] + bv1.z, acc[i][7] + bv1.w};
      *reinterpret_cast<float4*>(Y + (size_t)gr * 832 + gc) = o0;
      *reinterpret_cast<float4*>(Y + (size_t)gr * 832 + gc + 4) = o1;
    }
  }
}

// ---- per-node post: skip_out, zero accum slots, att scalars, m, XG ------
__global__ __launch_bounds__(256) void post_k(float* __restrict__ Y,
    const float* __restrict__ att_src, const float* __restrict__ att_dst,
    float* __restrict__ as_, float* __restrict__ ad_, float* __restrict__ m,
    __hip_bfloat16* __restrict__ XG) {
  int n = blockIdx.x * 4 + (threadIdx.x >> 6);
  if (n >= NN) return;
  int h = threadIdx.x & 63;
  float* y = Y + (size_t)n * 832;
  float fsb = y[h];
  float fsg = y[64 + h];
  float xs  = y[128 + h];
  float so  = fmaxf(fsg * xs + fsb, 0.f);
  float xph = y[768 + h];
  __hip_bfloat16* xg = XG + (size_t)n * 256;
  xg[h]       = __float2bfloat16(xph);
  xg[64 + h]  = __float2bfloat16(y[192 + h]);
  xg[128 + h] = __float2bfloat16(y[256 + h]);
  xg[192 + h] = __float2bfloat16(y[320 + h]);
  float pa = xph * att_src[h], pd = xph * att_dst[h];
  #pragma unroll
  for (int off = 32; off > 0; off >>= 1) {
    pa += __shfl_xor(pa, off);
    pd += __shfl_xor(pd, off);
  }
  y[h] = so;            // skip_out
  y[64 + h] = 0.f;      // agg accumulator slot
  y[128 + h] = 0.f;     // S accumulator slot
  if (h == 0) {
    as_[n] = pa; ad_[n] = pd;
    m[n] = leaky02(pa + pd);     // self-loop seeds the max
  }
}

// ---- edge-parallel: per-(dst,type) counts + softmax max -----------------
__global__ void edge_scalar_k(const int* __restrict__ ei, const int* __restrict__ et,
                              const float* __restrict__ as_, const float* __restrict__ ad_,
                              int* __restrict__ cnt, float* __restrict__ m) {
  int e = blockIdx.x * blockDim.x + threadIdx.x;
  if (e >= EE) return;
  int src = ei[e], dst = ei[EE + e], t = et[e];
  atomicAdd(&cnt[dst * RR + t], 1);
  atomicMaxF(&m[dst], leaky02(as_[src] + ad_[dst]));
}

// ---- 3-phase parallel exclusive scan (deg derived from cnt) -------------
#define NT 196   // ceil(50000/256)
__global__ __launch_bounds__(256) void scanA_k(const int* __restrict__ cnt,
    int* __restrict__ off, int* __restrict__ tsum) {
  __shared__ int s[256];
  int t = threadIdx.x, idx = blockIdx.x * 256 + t;
  int v = 0;
  if (idx < NN) v = cnt[3 * idx] + cnt[3 * idx + 1] + cnt[3 * idx + 2];
  s[t] = v;
  __syncthreads();
  for (int ofs = 1; ofs < 256; ofs <<= 1) {
    int u = (t >= ofs) ? s[t - ofs] : 0;
    __syncthreads();
    s[t] += u;
    __syncthreads();
  }
  if (idx < NN) off[idx] = s[t] - v;
  if (t == 255) tsum[blockIdx.x] = s[255];
}

__global__ __launch_bounds__(256) void scanB_k(const int* __restrict__ tsum,
    int* __restrict__ tbase, int* __restrict__ off) {
  __shared__ int s[256];
  int t = threadIdx.x;
  int v = (t < NT) ? tsum[t] : 0;
  s[t] = v;
  __syncthreads();
  for (int ofs = 1; ofs < 256; ofs <<= 1) {
    int u = (t >= ofs) ? s[t - ofs] : 0;
    __syncthreads();
    s[t] += u;
    __syncthreads();
  }
  if (t < NT) tbase[t] = s[t] - v;
  if (t == 255) off[NN] = s[255];
}

__global__ __launch_bounds__(256) void scanC_k(int* __restrict__ off,
    const int* __restrict__ tbase) {
  int idx = blockIdx.x * 256 + threadIdx.x;
  if (idx < NN) off[idx] += tbase[blockIdx.x];
}

// ---- CSR scatter: sorted (src|type) + sdst ------------------------------
__global__ void scatter_k(const int* __restrict__ ei, const int* __restrict__ et,
                          const int* __restrict__ off, int* __restrict__ fill,
                          int* __restrict__ sorted, int* __restrict__ sdst) {
  int e = blockIdx.x * blockDim.x + threadIdx.x;
  if (e >= EE) return;
  int src = ei[e], dst = ei[EE + e], t = et[e];
  int pos = off[dst] + atomicAdd(&fill[dst], 1);
  sorted[pos] = src | (t << 20);
  sdst[pos] = dst;
}

// ---- THE edge pass: wave-per-edge, sorted order, LDS run-reduction ------
#define EPB 8   // edges (waves) per block; EE % EPB == 0
__global__ __launch_bounds__(512) void edge8_k(const int* __restrict__ sorted,
    const int* __restrict__ sdst, float* __restrict__ Y,
    const __hip_bfloat16* __restrict__ XG,
    const float* __restrict__ as_, const float* __restrict__ ad_,
    const float* __restrict__ m, const int* __restrict__ cnt,
    float* __restrict__ den) {
  __shared__ float s_v[EPB][64];
  __shared__ float s_u[EPB][64];
  __shared__ float s_wt[EPB];
  __shared__ int   s_d[EPB];
  int wid = threadIdx.x >> 6, h = threadIdx.x & 63;
  int e = blockIdx.x * EPB + wid;
  int dst = -1;
  if (e < EE) {
    int pk = sorted[e];
    int src = pk & 0xFFFFF; if (src >= NN) src = NN - 1;
    int t = pk >> 20; if (t > 2) t = 2;
    dst = sdst[e]; if ((unsigned)dst >= NN) dst = 0;
    const __hip_bfloat16* xg = XG + (size_t)src * 256;
    float xp = __bfloat162float(xg[h]);
    float xr = __bfloat162float(xg[64 + (t << 6) + h]);
    const float* yd = Y + (size_t)dst * 832;
    float beta  = yd[384 + (t << 7) + h];
    float gamma = yd[384 + (t << 7) + 64 + h];
    int c = cnt[dst * 3 + t];
    float invd = 1.f / (float)(c > 1 ? c : 1);
    float w = __expf(leaky02(as_[src] + ad_[dst]) - m[dst]);
    s_v[wid][h] = fmaxf(gamma * xr + beta, 0.f) * invd;
    s_u[wid][h] = w * xp;
    if (h == 0) s_wt[wid] = w;
  } else {
    s_v[wid][h] = 0.f; s_u[wid][h] = 0.f;
    if (h == 0) s_wt[wid] = 0.f;
  }
  if (h == 0) s_d[wid] = dst;
  __syncthreads();
  // leaders: first wave of each same-dst run emits fused atomics
  if (e < EE && (wid == 0 || s_d[wid - 1] != dst)) {
    float av = s_v[wid][h], au = s_u[wid][h], aw = s_wt[wid];
    int j = wid + 1;
    while (j < EPB && s_d[j] == dst) {
      av += s_v[j][h]; au += s_u[j][h]; aw += s_wt[j]; j++;
    }
    float* yd = Y + (size_t)dst * 832;
    atomicAdd(&yd[64 + h], av);          // agg (line-aligned 256B chunk)
    atomicAdd(&yd[128 + h], au);         // S
    if (h == 0) atomicAdd(&den[dst], aw);
  }
}

// ---- finalize per node: feats + graph boundaries ------------------------
__global__ __launch_bounds__(256) void feats_k(float* __restrict__ Y,
    const float* __restrict__ den, const float* __restrict__ m,
    const float* __restrict__ as_, const float* __restrict__ ad_,
    const float* __restrict__ gat_b, const int* __restrict__ gb,
    int* __restrict__ gstart, int* __restrict__ gend) {
  int n = blockIdx.x * 4 + (threadIdx.x >> 6);
  if (n >= NN) return;
  int h = threadIdx.x & 63;
  float* y = Y + (size_t)n * 832;
  float o1 = fmaxf(y[h] + y[64 + h], 0.f);
  float es = leaky02(as_[n] + ad_[n]);
  float wself = __expf(es - m[n]);
  float denf = den[n] + wself;
  float o2 = fmaxf((y[128 + h] + wself * y[768 + h]) / denf + gat_b[h], 0.f);
  y[192 + h] = o1;
  y[256 + h] = o2;
  if (h == 0) {
    int g = gb[n];
    atomicMin(&gstart[g], n);
    atomicMax(&gend[g], n);
  }
}

// ---- parallel pooling: 8 chunks per graph, atomic max/sum ---------------
__global__ __launch_bounds__(128) void pool_k(const float* __restrict__ Y,
    const int* __restrict__ gstart, const int* __restrict__ gend,
    float* __restrict__ pmax, float* __restrict__ psum) {
  int g = blockIdx.x, chunk = blockIdx.y, f = threadIdx.x;
  int s = gstart[g], e = gend[g];
  if (s > e || s >= NN || s < 0) return;
  if (e >= NN) e = NN - 1;
  int len = e - s + 1;
  int per = (len + 7) >> 3;
  int a = s + chunk * per;
  int bnd = a + per; if (bnd > e + 1) bnd = e + 1;
  if (a >= bnd) return;
  float mx = 0.f, sm = 0.f;          // feats >= 0 (both relu'd)
  for (int n = a; n < bnd; n++) {
    float v = Y[(size_t)n * 832 + 192 + f];
    mx = fmaxf(mx, v);
    sm += v;
  }
  atomicMaxFPos(&pmax[g * 128 + f], mx);
  atomicAdd(&psum[g * 128 + f], sm);
}

// ---- head MLP + log_softmax (fp32 out) ----------------------------------
__global__ __launch_bounds__(64) void head_k(const float* __restrict__ pmax,
    const float* __restrict__ psum, const int* __restrict__ gstart,
    const int* __restrict__ gend,
    const float* __restrict__ lin_W, const float* __restrict__ lin_b,
    const float* __restrict__ fc_W, const float* __restrict__ fc_b,
    float* __restrict__ out) {
  __shared__ float p[256];
  __shared__ float hid[64];
  __shared__ float lg[CC];
  __shared__ float lse;
  int g = blockIdx.x, t = threadIdx.x;
  int s = gstart[g], e = gend[g];
  int cnt = (s <= e && s < NN && s >= 0) ? (e - s + 1) : 0;
  float invc = 1.f / (float)(cnt > 1 ? cnt : 1);
  for (int i = t; i < 256; i += 64)
    p[i] = (i < 128) ? pmax[g * 128 + i] : psum[g * 128 + (i - 128)] * invc;
  __syncthreads();
  float acc = lin_b[t];
  for (int k = 0; k < 256; k++) acc += p[k] * lin_W[k * 64 + t];
  hid[t] = fmaxf(acc, 0.f);
  __syncthreads();
  if (t < CC) {
    float a = fc_b[t];
    for (int k = 0; k < 64; k++) a += hid[k] * fc_W[k * CC + t];
    lg[t] = a;
  }
  __syncthreads();
  if (t == 0) {
    float mx = lg[0];
    for (int i = 1; i < CC; i++) mx = fmaxf(mx, lg[i]);
    float sum = 0.f;
    for (int i = 0; i < CC; i++) sum += expf(lg[i] - mx);
    lse = mx + logf(sum);
  }
  __syncthreads();
  if (t < CC) out[g * CC + t] = lg[t] - lse;
}

extern "C" void kernel_launch(void* const* d_in, const int* in_sizes, int n_in,
                              void* d_out, int out_size, void* d_ws, size_t ws_size,
                              hipStream_t stream) {
  const float* x            = (const float*)d_in[0];
  const int*   edge_index   = (const int*)d_in[1];
  const int*   edge_type    = (const int*)d_in[2];
  const int*   graph_batch  = (const int*)d_in[3];
  const float* film_lin_W   = (const float*)d_in[4];
  const float* film_film_W  = (const float*)d_in[5];
  const float* film_film_b  = (const float*)d_in[6];
  const float* skip_W       = (const float*)d_in[7];
  const float* skip_film_W  = (const float*)d_in[8];
  const float* skip_film_b  = (const float*)d_in[9];
  const float* gat_W        = (const float*)d_in[10];
  const float* att_src      = (const float*)d_in[11];
  const float* att_dst      = (const float*)d_in[12];
  const float* gat_b        = (const float*)d_in[13];
  const float* lin_W        = (const float*)d_in[14];
  const float* lin_b        = (const float*)d_in[15];
  const float* fc_W         = (const float*)d_in[16];
  const float* fc_b         = (const float*)d_in[17];
  float* out                = (float*)d_out;

  float* ws = (float*)d_ws;
  const size_t N = NN, E = EE, G = GG;
  size_t oY      = 0;                       // N*832
  size_t oXG     = N * 832;                 // N*128 float slots (N*256 bf16)
  size_t oAs     = oXG + N * 128;           // N
  size_t oAd     = oAs + N;                 // N
  size_t oM      = oAd + N;                 // N (init by post_k)
  size_t oW      = oM + N;                  // 64*832
  size_t oBias   = oW + 64 * 832;           // 832
  size_t oPmax   = oBias + 832;             // G*128 } zero region start
  size_t oPsum   = oPmax + G * 128;         // G*128 }
  size_t oGend   = oPsum + G * 128;         // G     }
  size_t oCnt    = oGend + G;               // 3N    }
  size_t oFill   = oCnt + 3 * N;            // N     }
  size_t oDen    = oFill + N;               // N     } zero region end
  size_t oGstart = oDen + N;                // G (0x7f)
  size_t oOff    = oGstart + G;             // N+1
  size_t oTsum   = oOff + N + 1;            // 256
  size_t oTbase  = oTsum + 256;             // 256
  size_t oSorted = oTbase + 256;            // E
  size_t oSdst   = oSorted + E;             // E

  float* Y      = ws + oY;
  __hip_bfloat16* XG = (__hip_bfloat16*)(ws + oXG);
  float* as_    = ws + oAs;
  float* ad_    = ws + oAd;
  float* m      = ws + oM;
  float* Wcat   = ws + oW;
  float* bias   = ws + oBias;
  float* pmax   = ws + oPmax;
  float* psum   = ws + oPsum;
  int*   gend   = (int*)(ws + oGend);
  int*   cnt    = (int*)(ws + oCnt);
  int*   fill   = (int*)(ws + oFill);
  float* den    = ws + oDen;
  int*   gstart = (int*)(ws + oGstart);
  int*   off    = (int*)(ws + oOff);
  int*   tsum   = (int*)(ws + oTsum);
  int*   tbase  = (int*)(ws + oTbase);
  int*   sorted = (int*)(ws + oSorted);
  int*   sdst   = (int*)(ws + oSdst);

  size_t zeroFloats = oGstart - oPmax;   // pmax,psum,gend,cnt,fill,den (~1.1MB)
  hipMemsetAsync(pmax, 0, zeroFloats * sizeof(float), stream);
  hipMemsetAsync(gstart, 0x7f, G * sizeof(int), stream);

  pack_w_k<<<(64 * 832 + 832 + 255) / 256, 256, 0, stream>>>(
      skip_film_W, skip_W, film_lin_W, film_film_W, gat_W,
      skip_film_b, film_film_b, Wcat, bias);
  gemm_k<<<dim3((NN + 63) / 64, 7), 256, 0, stream>>>(x, Wcat, bias, Y);
  post_k<<<(NN + 3) / 4, 256, 0, stream>>>(Y, att_src, att_dst, as_, ad_, m, XG);
  edge_scalar_k<<<(EE + 255) / 256, 256, 0, stream>>>(edge_index, edge_type,
                                                      as_, ad_, cnt, m);
  scanA_k<<<NT, 256, 0, stream>>>(cnt, off, tsum);
  scanB_k<<<1, 256, 0, stream>>>(tsum, tbase, off);
  scanC_k<<<NT, 256, 0, stream>>>(off, tbase);
  scatter_k<<<(EE + 255) / 256, 256, 0, stream>>>(edge_index, edge_type,
                                                  off, fill, sorted, sdst);
  edge8_k<<<EE / EPB, 512, 0, stream>>>(sorted, sdst, Y, XG, as_, ad_,
                                        m, cnt, den);
  feats_k<<<(NN + 3) / 4, 256, 0, stream>>>(Y, den, m, as_, ad_, gat_b,
                                            graph_batch, gstart, gend);
  pool_k<<<dim3(GG, 8), 128, 0, stream>>>(Y, gstart, gend, pmax, psum);
  head_k<<<GG, 64, 0, stream>>>(pmax, psum, gstart, gend,
                                lin_W, lin_b, fc_W, fc_b, out);
}

// Round 8
// 401.429 us; speedup vs baseline: 2.2618x; 2.2618x over previous
//
#include <hip/hip_runtime.h>
#include <hip/hip_bf16.h>

// Problem constants (from reference)
#define NN 50000
#define EE 800000
#define GG 64
#define RR 3
#define CC 10
// Y layout per node (832 cols): [0:128 fs | 128:192 xs | 192:384 xr(r=0..2) |
//                                384:768 fm(r, beta|gamma) | 768:832 xp]
// post_k: writes skip_out into col 0:64, builds XG bf16 [xp|xr0|xr1|xr2].
// dst_k: writes feats into cols 192:320; graph boundaries via sorted-gb
// neighbor compare (NO atomics -- 64-address atomicMin/Max serialized at
// ~350us in rounds 3-7; that was the hidden floor).

__device__ inline float leaky02(float x) { return x > 0.f ? x : 0.2f * x; }

// valid for non-negative floats only (int compare == float compare there)
__device__ inline void atomicMaxFPos(float* addr, float v) {
  atomicMax((int*)addr, __float_as_int(v));
}

// ---- pack node weights into Wcat (64 x 832) + bias vec (832) ------------
__global__ void pack_w_k(const float* __restrict__ skip_film_W,
                         const float* __restrict__ skip_W,
                         const float* __restrict__ film_lin_W,
                         const float* __restrict__ film_film_W,
                         const float* __restrict__ gat_W,
                         const float* __restrict__ skip_film_b,
                         const float* __restrict__ film_film_b,
                         float* __restrict__ Wcat, float* __restrict__ bias) {
  int idx = blockIdx.x * blockDim.x + threadIdx.x;
  if (idx >= 64 * 832 + 832) return;
  if (idx >= 64 * 832) {
    int c = idx - 64 * 832;
    float b = 0.f;
    if (c < 128) b = skip_film_b[c];
    else if (c >= 384 && c < 768) b = film_film_b[c - 384];
    bias[c] = b;
    return;
  }
  int k = idx / 832, c = idx % 832;
  float v;
  if (c < 128)      v = skip_film_W[k * 128 + c];
  else if (c < 192) v = skip_W[k * 64 + (c - 128)];
  else if (c < 384) { int cc = c - 192, r = cc >> 6, h = cc & 63;
                      v = film_lin_W[(r * 64 + k) * 64 + h]; }
  else if (c < 768) { int cc = c - 384, r = cc >> 7, j = cc & 127;
                      v = film_film_W[(r * 64 + k) * 128 + j]; }
  else              v = gat_W[k * 64 + (c - 768)];
  Wcat[idx] = v;
}

// ---- X(50000x64) @ Wcat(64x832) + bias -> Y -----------------------------
__global__ __launch_bounds__(256) void gemm_k(const float* __restrict__ X,
                                              const float* __restrict__ W,
                                              const float* __restrict__ bias,
                                              float* __restrict__ Y) {
  __shared__ __align__(16) float As[64][65];
  __shared__ __align__(16) float Bs[64][128];
  const int tid = threadIdx.x;
  const int row0 = blockIdx.x * 64;
  const int col0 = blockIdx.y * 128;

  #pragma unroll
  for (int s = 0; s < 4; s++) {
    int q = s * 256 + tid;
    int r = q >> 4;
    int c4 = (q & 15) << 2;
    int gr = row0 + r;
    float4 v = make_float4(0.f, 0.f, 0.f, 0.f);
    if (gr < NN) v = *reinterpret_cast<const float4*>(X + (size_t)gr * 64 + c4);
    As[r][c4 + 0] = v.x; As[r][c4 + 1] = v.y;
    As[r][c4 + 2] = v.z; As[r][c4 + 3] = v.w;
  }
  #pragma unroll
  for (int s = 0; s < 8; s++) {
    int q = s * 256 + tid;
    int r = q >> 5;
    int c4 = (q & 31) << 2;
    int gc = col0 + c4;
    float4 v = make_float4(0.f, 0.f, 0.f, 0.f);
    if (gc + 3 < 832) v = *reinterpret_cast<const float4*>(W + (size_t)r * 832 + gc);
    *reinterpret_cast<float4*>(&Bs[r][c4]) = v;
  }
  __syncthreads();

  const int tx = tid & 15, ty = tid >> 4;
  float acc[4][8] = {};
  #pragma unroll 8
  for (int k = 0; k < 64; k++) {
    float a0 = As[ty * 4 + 0][k], a1 = As[ty * 4 + 1][k];
    float a2 = As[ty * 4 + 2][k], a3 = As[ty * 4 + 3][k];
    const float4* bp = reinterpret_cast<const float4*>(&Bs[k][tx * 8]);
    float4 b0 = bp[0], b1 = bp[1];
    float bb[8] = {b0.x, b0.y, b0.z, b0.w, b1.x, b1.y, b1.z, b1.w};
    #pragma unroll
    for (int j = 0; j < 8; j++) {
      acc[0][j] += a0 * bb[j]; acc[1][j] += a1 * bb[j];
      acc[2][j] += a2 * bb[j]; acc[3][j] += a3 * bb[j];
    }
  }
  int gc = col0 + tx * 8;
  if (gc + 7 < 832) {
    float4 bv0 = *reinterpret_cast<const float4*>(bias + gc);
    float4 bv1 = *reinterpret_cast<const float4*>(bias + gc + 4);
    #pragma unroll
    for (int i = 0; i < 4; i++) {
      int gr = row0 + ty * 4 + i;
      if (gr >= NN) continue;
      float4 o0 = {acc[i][0] + bv0.x, acc[i][1] + bv0.y,
                   acc[i][2] + bv0.z, acc[i][3] + bv0.w};
      float4 o1 = {acc[i][4] + bv1.x, acc[i][5] + bv1.y,
                   acc[i][6] + bv1.z, acc[i][7] + bv1.w};
      *reinterpret_cast<float4*>(Y + (size_t)gr * 832 + gc) = o0;
      *reinterpret_cast<float4*>(Y + (size_t)gr * 832 + gc + 4) = o1;
    }
  }
}

// ---- per-node post: skip_out, attention scalars, XG bf16 build ----------
__global__ __launch_bounds__(256) void post_k(float* __restrict__ Y,
    const float* __restrict__ att_src, const float* __restrict__ att_dst,
    float* __restrict__ as_, float* __restrict__ ad_,
    __hip_bfloat16* __restrict__ XG) {
  int n = blockIdx.x * 4 + (threadIdx.x >> 6);
  if (n >= NN) return;
  int h = threadIdx.x & 63;
  float* y = Y + (size_t)n * 832;
  float fsb = y[h];
  float fsg = y[64 + h];
  float xs  = y[128 + h];
  float so  = fmaxf(fsg * xs + fsb, 0.f);
  float xph = y[768 + h];
  __hip_bfloat16* xg = XG + (size_t)n * 256;
  xg[h]       = __float2bfloat16(xph);
  xg[64 + h]  = __float2bfloat16(y[192 + h]);
  xg[128 + h] = __float2bfloat16(y[256 + h]);
  xg[192 + h] = __float2bfloat16(y[320 + h]);
  float pa = xph * att_src[h], pd = xph * att_dst[h];
  #pragma unroll
  for (int off = 32; off > 0; off >>= 1) {
    pa += __shfl_xor(pa, off);
    pd += __shfl_xor(pd, off);
  }
  y[h] = so;
  if (h == 0) { as_[n] = pa; ad_[n] = pd; }
}

// ---- CSR build: count ----------------------------------------------------
__global__ void count_k(const int* __restrict__ ei, int* __restrict__ deg) {
  int e = blockIdx.x * blockDim.x + threadIdx.x;
  if (e >= EE) return;
  atomicAdd(&deg[ei[EE + e]], 1);
}

// ---- 3-phase parallel exclusive scan ------------------------------------
#define NT 196   // ceil(50000/256)
__global__ __launch_bounds__(256) void scanA_k(const int* __restrict__ deg,
    int* __restrict__ off, int* __restrict__ tsum) {
  __shared__ int s[256];
  int t = threadIdx.x, idx = blockIdx.x * 256 + t;
  int v = (idx < NN) ? deg[idx] : 0;
  s[t] = v;
  __syncthreads();
  for (int ofs = 1; ofs < 256; ofs <<= 1) {
    int u = (t >= ofs) ? s[t - ofs] : 0;
    __syncthreads();
    s[t] += u;
    __syncthreads();
  }
  if (idx < NN) off[idx] = s[t] - v;
  if (t == 255) tsum[blockIdx.x] = s[255];
}

__global__ __launch_bounds__(256) void scanB_k(const int* __restrict__ tsum,
    int* __restrict__ tbase, int* __restrict__ off) {
  __shared__ int s[256];
  int t = threadIdx.x;
  int v = (t < NT) ? tsum[t] : 0;
  s[t] = v;
  __syncthreads();
  for (int ofs = 1; ofs < 256; ofs <<= 1) {
    int u = (t >= ofs) ? s[t - ofs] : 0;
    __syncthreads();
    s[t] += u;
    __syncthreads();
  }
  if (t < NT) tbase[t] = s[t] - v;
  if (t == 255) off[NN] = s[255];
}

__global__ __launch_bounds__(256) void scanC_k(int* __restrict__ off,
    const int* __restrict__ tbase) {
  int idx = blockIdx.x * 256 + threadIdx.x;
  if (idx < NN) off[idx] += tbase[blockIdx.x];
}

// ---- CSR build: scatter (src|type packed) -------------------------------
__global__ void scatter_k(const int* __restrict__ ei, const int* __restrict__ et,
                          const int* __restrict__ off, int* __restrict__ fill,
                          int* __restrict__ sorted) {
  int e = blockIdx.x * blockDim.x + threadIdx.x;
  if (e >= EE) return;
  int src = ei[e], dst = ei[EE + e], t = et[e];
  int pos = off[dst] + atomicAdd(&fill[dst], 1);
  sorted[pos] = src | (t << 20);
}

// ---- fused per-dst with cooperative block-level gather into LDS ----------
// Block = 4 nodes (one per wave). Per round: 16 edges/node. 256 threads
// cooperatively fetch the 128 needed XG rows (128B each) as 8-lane x 16B
// segments. Graph boundaries: sorted-gb neighbor compare, plain stores.
#define RPN 16    // edges per node per round
#define CAPE 256  // max edges per block window (4 x Poisson(16); P(>256)~0)

__global__ __launch_bounds__(256) void dst_k(const int* __restrict__ sorted,
    const int* __restrict__ off, float* __restrict__ Y,
    const __hip_bfloat16* __restrict__ XG,
    const float* __restrict__ as_, const float* __restrict__ ad_,
    const float* __restrict__ gat_b, const int* __restrict__ gb,
    int* __restrict__ gstart, int* __restrict__ gend) {
  __shared__ int   s_pk[CAPE];
  __shared__ float s_as[CAPE];
  __shared__ __align__(16) __hip_bfloat16 s_rows[64][2][64];  // 16 KB
  __shared__ int s_b[4], s_deg[4];

  int tid = threadIdx.x;
  int wid = tid >> 6, h = tid & 63;
  int n0 = blockIdx.x * 4;
  int n = n0 + wid;                      // always < NN (50000 = 12500*4)

  int o0 = off[n0];
  int T = off[n0 + 4] - o0; if (T > CAPE) T = CAPE;

  // prefetch packed edges + as_[src] for the whole block window (coalesced)
  if (tid < T) {
    int pk = sorted[o0 + tid];
    s_pk[tid] = pk;
    int s = pk & 0xFFFFF; if (s >= NN) s = NN - 1;
    s_as[tid] = as_[s];
  }
  if (h == 0) {
    int on = off[n], on1 = off[n + 1];
    int b = on - o0, d = on1 - on;
    if (b > CAPE) b = CAPE;
    if (b + d > CAPE) d = CAPE - b;
    s_b[wid] = b; s_deg[wid] = d;
  }
  __syncthreads();

  int myb = s_b[wid], mydeg = s_deg[wid];
  int dmax = max(max(s_deg[0], s_deg[1]), max(s_deg[2], s_deg[3]));
  int rounds = (dmax + RPN - 1) / RPN;

  float* yd = Y + (size_t)n * 832;
  float b0 = yd[384 + h], g0 = yd[448 + h];
  float b1 = yd[512 + h], g1 = yd[576 + h];
  float b2 = yd[640 + h], g2 = yd[704 + h];
  float adn = ad_[n];
  float m = leaky02(as_[n] + adn);     // self-loop seeds softmax state
  float den = 1.f;
  float S = yd[768 + h];               // self xp (fp32)
  float f0 = 0.f, f1 = 0.f, f2 = 0.f;
  int c0 = 0, c1 = 0, c2 = 0;

  const int grp = tid >> 3, lane8 = tid & 7;   // 32 groups of 8 lanes

  for (int r = 0; r < rounds; r++) {
    int e0 = r * RPN;
    // ---- cooperative gather: 128 rows (64 slots x {xp, xr_t}) ----
    #pragma unroll
    for (int k = 0; k < 4; k++) {
      int ri = grp + 32 * k;            // 0..127
      int slot = ri & 63;               // node wid_s = slot>>4, j = slot&15
      int part = ri >> 6;               // 0 = xp, 1 = xr_t
      int wd = slot >> 4, j = slot & 15;
      int jj = e0 + j;
      if (jj < s_deg[wd]) {
        int be = (s_b[wd] + jj) & (CAPE - 1);
        int pk = s_pk[be];
        int src = pk & 0xFFFFF; if (src >= NN) src = NN - 1;
        int t = pk >> 20;
        const __hip_bfloat16* row = XG + (size_t)src * 256
                                  + (part ? (64 + (t << 6)) : 0);
        uint4 v = *reinterpret_cast<const uint4*>(row + lane8 * 8);
        *reinterpret_cast<uint4*>(&s_rows[slot][part][lane8 * 8]) = v;
      }
    }
    __syncthreads();
    // ---- consume: wave `wid` processes its node's <=16 edges from LDS ----
    int cn = mydeg - e0; if (cn > RPN) cn = RPN;
    if (cn > 0) {
      float e = -1e30f;
      if (h < cn) e = leaky02(s_as[(myb + e0 + h) & (CAPE - 1)] + adn);
      float cm = e;
      #pragma unroll
      for (int ofs = 32; ofs > 0; ofs >>= 1) cm = fmaxf(cm, __shfl_xor(cm, ofs));
      float mn = fmaxf(m, cm);
      float w = (h < cn) ? __expf(e - mn) : 0.f;
      float ds = w;
      #pragma unroll
      for (int ofs = 32; ofs > 0; ofs >>= 1) ds += __shfl_xor(ds, ofs);
      float sc = __expf(m - mn);
      den = den * sc + ds;
      S *= sc;
      m = mn;
      for (int j = 0; j < cn; j++) {
        float wj = __shfl(w, j);
        int pkj = s_pk[(myb + e0 + j) & (CAPE - 1)];  // uniform -> broadcast
        int tj = pkj >> 20;
        int slot = wid * RPN + j;
        float xp = __bfloat162float(s_rows[slot][0][h]);
        float xr = __bfloat162float(s_rows[slot][1][h]);
        S += wj * xp;
        float gt = tj == 0 ? g0 : (tj == 1 ? g1 : g2);
        float bt = tj == 0 ? b0 : (tj == 1 ? b1 : b2);
        float msg = fmaxf(gt * xr + bt, 0.f);
        if (tj == 0)      { f0 += msg; c0++; }
        else if (tj == 1) { f1 += msg; c1++; }
        else              { f2 += msg; c2++; }
      }
    }
    __syncthreads();
  }

  float agg = f0 / (float)(c0 > 1 ? c0 : 1)
            + f1 / (float)(c1 > 1 ? c1 : 1)
            + f2 / (float)(c2 > 1 ? c2 : 1);
  float o1 = fmaxf(yd[h] + agg, 0.f);
  float o2 = fmaxf(S / den + gat_b[h], 0.f);
  yd[192 + h] = o1;                 // feats stored in freed xr cols
  yd[256 + h] = o2;
  if (h == 0) {
    // graph_batch is sorted: boundary detection, contention-free stores
    int g = gb[n];
    if (n == 0 || gb[n - 1] != g)      gstart[g] = n;
    if (n == NN - 1 || gb[n + 1] != g) gend[g] = n;
  }
}

// ---- parallel pooling: 8 chunks per graph, atomic max/sum ---------------
__global__ __launch_bounds__(128) void pool_k(const float* __restrict__ Y,
    const int* __restrict__ gstart, const int* __restrict__ gend,
    float* __restrict__ pmax, float* __restrict__ psum) {
  int g = blockIdx.x, chunk = blockIdx.y, f = threadIdx.x;
  int s = gstart[g], e = gend[g];
  if (s > e || s >= NN || s < 0) return;
  if (e >= NN) e = NN - 1;
  int len = e - s + 1;
  int per = (len + 7) >> 3;
  int a = s + chunk * per;
  int bnd = a + per; if (bnd > e + 1) bnd = e + 1;
  if (a >= bnd) return;
  float mx = 0.f, sm = 0.f;          // feats >= 0 (both relu'd)
  for (int n = a; n < bnd; n++) {
    float v = Y[(size_t)n * 832 + 192 + f];
    mx = fmaxf(mx, v);
    sm += v;
  }
  atomicMaxFPos(&pmax[g * 128 + f], mx);
  atomicAdd(&psum[g * 128 + f], sm);
}

// ---- head MLP + log_softmax (fp32 out) ----------------------------------
__global__ __launch_bounds__(64) void head_k(const float* __restrict__ pmax,
    const float* __restrict__ psum, const int* __restrict__ gstart,
    const int* __restrict__ gend,
    const float* __restrict__ lin_W, const float* __restrict__ lin_b,
    const float* __restrict__ fc_W, const float* __restrict__ fc_b,
    float* __restrict__ out) {
  __shared__ float p[256];
  __shared__ float hid[64];
  __shared__ float lg[CC];
  __shared__ float lse;
  int g = blockIdx.x, t = threadIdx.x;
  int s = gstart[g], e = gend[g];
  int cnt = (s <= e && s < NN && s >= 0) ? (e - s + 1) : 0;
  float invc = 1.f / (float)(cnt > 1 ? cnt : 1);
  for (int i = t; i < 256; i += 64)
    p[i] = (i < 128) ? pmax[g * 128 + i] : psum[g * 128 + (i - 128)] * invc;
  __syncthreads();
  float acc = lin_b[t];
  for (int k = 0; k < 256; k++) acc += p[k] * lin_W[k * 64 + t];
  hid[t] = fmaxf(acc, 0.f);
  __syncthreads();
  if (t < CC) {
    float a = fc_b[t];
    for (int k = 0; k < 64; k++) a += hid[k] * fc_W[k * CC + t];
    lg[t] = a;
  }
  __syncthreads();
  if (t == 0) {
    float mx = lg[0];
    for (int i = 1; i < CC; i++) mx = fmaxf(mx, lg[i]);
    float sum = 0.f;
    for (int i = 0; i < CC; i++) sum += expf(lg[i] - mx);
    lse = mx + logf(sum);
  }
  __syncthreads();
  if (t < CC) out[g * CC + t] = lg[t] - lse;
}

extern "C" void kernel_launch(void* const* d_in, const int* in_sizes, int n_in,
                              void* d_out, int out_size, void* d_ws, size_t ws_size,
                              hipStream_t stream) {
  const float* x            = (const float*)d_in[0];
  const int*   edge_index   = (const int*)d_in[1];
  const int*   edge_type    = (const int*)d_in[2];
  const int*   graph_batch  = (const int*)d_in[3];
  const float* film_lin_W   = (const float*)d_in[4];
  const float* film_film_W  = (const float*)d_in[5];
  const float* film_film_b  = (const float*)d_in[6];
  const float* skip_W       = (const float*)d_in[7];
  const float* skip_film_W  = (const float*)d_in[8];
  const float* skip_film_b  = (const float*)d_in[9];
  const float* gat_W        = (const float*)d_in[10];
  const float* att_src      = (const float*)d_in[11];
  const float* att_dst      = (const float*)d_in[12];
  const float* gat_b        = (const float*)d_in[13];
  const float* lin_W        = (const float*)d_in[14];
  const float* lin_b        = (const float*)d_in[15];
  const float* fc_W         = (const float*)d_in[16];
  const float* fc_b         = (const float*)d_in[17];
  float* out                = (float*)d_out;

  float* ws = (float*)d_ws;
  const size_t N = NN, E = EE, G = GG;
  size_t oY      = 0;                       // N*832
  size_t oXG     = N * 832;                 // N*128 float slots (N*256 bf16)
  size_t oAs     = oXG + N * 128;           // N
  size_t oAd     = oAs + N;                 // N
  size_t oW      = oAd + N;                 // 64*832
  size_t oBias   = oW + 64 * 832;           // 832
  size_t oPmax   = oBias + 832;             // G*128 } zero region
  size_t oPsum   = oPmax + G * 128;         // G*128 }
  size_t oGend   = oPsum + G * 128;         // G     }
  size_t oDeg    = oGend + G;               // N     }
  size_t oFill   = oDeg + N;                // N     }
  size_t oGstart = oFill + N;               // G (0x7f)
  size_t oOff    = oGstart + G;             // N+1
  size_t oTsum   = oOff + N + 1;            // 256
  size_t oTbase  = oTsum + 256;             // 256
  size_t oSorted = oTbase + 256;            // E

  float* Y      = ws + oY;
  __hip_bfloat16* XG = (__hip_bfloat16*)(ws + oXG);
  float* as_    = ws + oAs;
  float* ad_    = ws + oAd;
  float* Wcat   = ws + oW;
  float* bias   = ws + oBias;
  float* pmax   = ws + oPmax;
  float* psum   = ws + oPsum;
  int*   gend   = (int*)(ws + oGend);
  int*   deg    = (int*)(ws + oDeg);
  int*   fill   = (int*)(ws + oFill);
  int*   gstart = (int*)(ws + oGstart);
  int*   off    = (int*)(ws + oOff);
  int*   tsum   = (int*)(ws + oTsum);
  int*   tbase  = (int*)(ws + oTbase);
  int*   sorted = (int*)(ws + oSorted);

  size_t zeroFloats = oGstart - oPmax;   // pmax,psum,gend,deg,fill
  hipMemsetAsync(pmax, 0, zeroFloats * sizeof(float), stream);
  hipMemsetAsync(gstart, 0x7f, G * sizeof(int), stream);

  pack_w_k<<<(64 * 832 + 832 + 255) / 256, 256, 0, stream>>>(
      skip_film_W, skip_W, film_lin_W, film_film_W, gat_W,
      skip_film_b, film_film_b, Wcat, bias);
  gemm_k<<<dim3((NN + 63) / 64, 7), 256, 0, stream>>>(x, Wcat, bias, Y);
  post_k<<<(NN + 3) / 4, 256, 0, stream>>>(Y, att_src, att_dst, as_, ad_, XG);
  count_k<<<(EE + 255) / 256, 256, 0, stream>>>(edge_index, deg);
  scanA_k<<<NT, 256, 0, stream>>>(deg, off, tsum);
  scanB_k<<<1, 256, 0, stream>>>(tsum, tbase, off);
  scanC_k<<<NT, 256, 0, stream>>>(off, tbase);
  scatter_k<<<(EE + 255) / 256, 256, 0, stream>>>(edge_index, edge_type,
                                                  off, fill, sorted);
  dst_k<<<NN / 4, 256, 0, stream>>>(sorted, off, Y, XG, as_, ad_,
                                    gat_b, graph_batch, gstart, gend);
  pool_k<<<dim3(GG, 8), 128, 0, stream>>>(Y, gstart, gend, pmax, psum);
  head_k<<<GG, 64, 0, stream>>>(pmax, psum, gstart, gend,
                                lin_W, lin_b, fc_W, fc_b, out);
}

// Round 9
// 362.488 us; speedup vs baseline: 2.5048x; 1.1074x over previous
//
#include <hip/hip_runtime.h>
#include <hip/hip_bf16.h>

// Problem constants (from reference)
#define NN 50000
#define EE 800000
#define GG 64
#define RR 3
#define CC 10
// Y layout per node (832 cols): [0:128 fs | 128:192 xs | 192:384 xr(r=0..2) |
//                                384:768 fm(r, beta|gamma) | 768:832 xp]
// gemm: bf16 MFMA (X,W pre-converted to bf16), fp32 accum, bias epilogue.
// post_k: writes skip_out into col 0:64, builds XG bf16 [xp|xr0|xr1|xr2].
// dst_k: feats -> cols 192:320; graph boundaries via sorted-gb neighbor
// compare (NO atomics -- 64-address atomicMin/Max serialized ~350us, r3-r7).

typedef __attribute__((ext_vector_type(8))) short bf16x8;
typedef __attribute__((ext_vector_type(4))) float f32x4;

__device__ inline float leaky02(float x) { return x > 0.f ? x : 0.2f * x; }

// valid for non-negative floats only (int compare == float compare there)
__device__ inline void atomicMaxFPos(float* addr, float v) {
  atomicMax((int*)addr, __float_as_int(v));
}

__device__ inline unsigned short f2bf(float f) {
  __hip_bfloat16 b = __float2bfloat16(f);
  return *reinterpret_cast<unsigned short*>(&b);
}

// ---- pack node weights into Wt bf16 [832][64] + bias vec (832) ----------
__global__ void pack_w_k(const float* __restrict__ skip_film_W,
                         const float* __restrict__ skip_W,
                         const float* __restrict__ film_lin_W,
                         const float* __restrict__ film_film_W,
                         const float* __restrict__ gat_W,
                         const float* __restrict__ skip_film_b,
                         const float* __restrict__ film_film_b,
                         unsigned short* __restrict__ Wt,
                         float* __restrict__ bias) {
  int idx = blockIdx.x * blockDim.x + threadIdx.x;
  if (idx >= 832 * 64 + 832) return;
  if (idx >= 832 * 64) {
    int c = idx - 832 * 64;
    float b = 0.f;
    if (c < 128) b = skip_film_b[c];
    else if (c >= 384 && c < 768) b = film_film_b[c - 384];
    bias[c] = b;
    return;
  }
  int c = idx >> 6, k = idx & 63;      // Wt[c][k] = Wcat[k][c]
  float v;
  if (c < 128)      v = skip_film_W[k * 128 + c];
  else if (c < 192) v = skip_W[k * 64 + (c - 128)];
  else if (c < 384) { int cc = c - 192, r = cc >> 6, h = cc & 63;
                      v = film_lin_W[(r * 64 + k) * 64 + h]; }
  else if (c < 768) { int cc = c - 384, r = cc >> 7, j = cc & 127;
                      v = film_film_W[(r * 64 + k) * 128 + j]; }
  else              v = gat_W[k * 64 + (c - 768)];
  Wt[idx] = f2bf(v);
}

// ---- X fp32 -> bf16 ------------------------------------------------------
__global__ void xcvt_k(const float* __restrict__ X,
                       unsigned short* __restrict__ Xbf) {
  int i = blockIdx.x * blockDim.x + threadIdx.x;
  int idx = i * 4;
  if (idx >= NN * 64) return;
  float4 v = *reinterpret_cast<const float4*>(X + idx);
  ushort4 o = {f2bf(v.x), f2bf(v.y), f2bf(v.z), f2bf(v.w)};
  *reinterpret_cast<ushort4*>(Xbf + idx) = o;
}

// ---- MFMA GEMM: Xbf(50000x64) @ Wt^T(64x832) + bias -> Y fp32 -----------
// Single-stage (K=64 total): LDS A 64x64, B(col-major) 128x64, both padded
// to 72 shorts/row (conflict-free ds_read_b128 for frags).
__global__ __launch_bounds__(256) void gemm_k(const unsigned short* __restrict__ Xbf,
                                              const unsigned short* __restrict__ Wt,
                                              const float* __restrict__ bias,
                                              float* __restrict__ Y) {
  __shared__ __align__(16) unsigned short As[64][72];
  __shared__ __align__(16) unsigned short Bs[128][72];
  const int tid = threadIdx.x;
  const int row0 = blockIdx.x * 64;
  const int col0 = blockIdx.y * 128;

  // A: 16 shorts/thread (2x uint4)
  {
    int r = tid >> 2, c0 = (tid & 3) * 16;
    int gr = row0 + r;
    uint4 v0 = {0, 0, 0, 0}, v1 = {0, 0, 0, 0};
    if (gr < NN) {
      const uint4* p = reinterpret_cast<const uint4*>(Xbf + (size_t)gr * 64 + c0);
      v0 = p[0]; v1 = p[1];
    }
    *reinterpret_cast<uint4*>(&As[r][c0])     = v0;
    *reinterpret_cast<uint4*>(&As[r][c0 + 8]) = v1;
  }
  // B: 32 shorts/thread (4x uint4); Wt is [col][k] so rows are contiguous
  {
    int c = tid >> 1, half = (tid & 1) * 32;
    int gc = col0 + c;
    uint4 v0 = {0,0,0,0}, v1 = {0,0,0,0}, v2 = {0,0,0,0}, v3 = {0,0,0,0};
    if (gc < 832) {
      const uint4* p = reinterpret_cast<const uint4*>(Wt + (size_t)gc * 64 + half);
      v0 = p[0]; v1 = p[1]; v2 = p[2]; v3 = p[3];
    }
    *reinterpret_cast<uint4*>(&Bs[c][half])      = v0;
    *reinterpret_cast<uint4*>(&Bs[c][half + 8])  = v1;
    *reinterpret_cast<uint4*>(&Bs[c][half + 16]) = v2;
    *reinterpret_cast<uint4*>(&Bs[c][half + 24]) = v3;
  }
  __syncthreads();

  const int w = tid >> 6, lane = tid & 63;
  const int m = lane & 15, q = lane >> 4;
  // A-frag: A[m=lane&15][k=q*8+j]
  bf16x8 a0 = *reinterpret_cast<const bf16x8*>(&As[16 * w + m][q * 8]);
  bf16x8 a1 = *reinterpret_cast<const bf16x8*>(&As[16 * w + m][32 + q * 8]);
  int rbase = row0 + 16 * w + q * 4;

  for (int ct = 0; ct < 8; ct++) {
    if (col0 + ct * 16 >= 832) break;          // wave-uniform
    // B-frag: B[k=q*8+j][n=lane&15]; Bs is col-major so contiguous in k
    bf16x8 b0 = *reinterpret_cast<const bf16x8*>(&Bs[ct * 16 + m][q * 8]);
    bf16x8 b1 = *reinterpret_cast<const bf16x8*>(&Bs[ct * 16 + m][32 + q * 8]);
    f32x4 acc = {0.f, 0.f, 0.f, 0.f};
    acc = __builtin_amdgcn_mfma_f32_16x16x32_bf16(a0, b0, acc, 0, 0, 0);
    acc = __builtin_amdgcn_mfma_f32_16x16x32_bf16(a1, b1, acc, 0, 0, 0);
    int gc = col0 + ct * 16 + m;               // C/D: col=lane&15
    float bv = bias[gc];
    #pragma unroll
    for (int rg = 0; rg < 4; rg++) {           // C/D: row=q*4+reg
      int gr = rbase + rg;
      if (gr < NN) Y[(size_t)gr * 832 + gc] = acc[rg] + bv;
    }
  }
}

// ---- per-node post: skip_out, attention scalars, XG bf16 build ----------
__global__ __launch_bounds__(256) void post_k(float* __restrict__ Y,
    const float* __restrict__ att_src, const float* __restrict__ att_dst,
    float* __restrict__ as_, float* __restrict__ ad_,
    __hip_bfloat16* __restrict__ XG) {
  int n = blockIdx.x * 4 + (threadIdx.x >> 6);
  if (n >= NN) return;
  int h = threadIdx.x & 63;
  float* y = Y + (size_t)n * 832;
  float fsb = y[h];
  float fsg = y[64 + h];
  float xs  = y[128 + h];
  float so  = fmaxf(fsg * xs + fsb, 0.f);
  float xph = y[768 + h];
  __hip_bfloat16* xg = XG + (size_t)n * 256;
  xg[h]       = __float2bfloat16(xph);
  xg[64 + h]  = __float2bfloat16(y[192 + h]);
  xg[128 + h] = __float2bfloat16(y[256 + h]);
  xg[192 + h] = __float2bfloat16(y[320 + h]);
  float pa = xph * att_src[h], pd = xph * att_dst[h];
  #pragma unroll
  for (int off = 32; off > 0; off >>= 1) {
    pa += __shfl_xor(pa, off);
    pd += __shfl_xor(pd, off);
  }
  y[h] = so;
  if (h == 0) { as_[n] = pa; ad_[n] = pd; }
}

// ---- CSR build: count ----------------------------------------------------
__global__ void count_k(const int* __restrict__ ei, int* __restrict__ deg) {
  int e = blockIdx.x * blockDim.x + threadIdx.x;
  if (e >= EE) return;
  atomicAdd(&deg[ei[EE + e]], 1);
}

// ---- 3-phase parallel exclusive scan ------------------------------------
#define NT 196   // ceil(50000/256)
__global__ __launch_bounds__(256) void scanA_k(const int* __restrict__ deg,
    int* __restrict__ off, int* __restrict__ tsum) {
  __shared__ int s[256];
  int t = threadIdx.x, idx = blockIdx.x * 256 + t;
  int v = (idx < NN) ? deg[idx] : 0;
  s[t] = v;
  __syncthreads();
  for (int ofs = 1; ofs < 256; ofs <<= 1) {
    int u = (t >= ofs) ? s[t - ofs] : 0;
    __syncthreads();
    s[t] += u;
    __syncthreads();
  }
  if (idx < NN) off[idx] = s[t] - v;
  if (t == 255) tsum[blockIdx.x] = s[255];
}

__global__ __launch_bounds__(256) void scanB_k(const int* __restrict__ tsum,
    int* __restrict__ tbase, int* __restrict__ off) {
  __shared__ int s[256];
  int t = threadIdx.x;
  int v = (t < NT) ? tsum[t] : 0;
  s[t] = v;
  __syncthreads();
  for (int ofs = 1; ofs < 256; ofs <<= 1) {
    int u = (t >= ofs) ? s[t - ofs] : 0;
    __syncthreads();
    s[t] += u;
    __syncthreads();
  }
  if (t < NT) tbase[t] = s[t] - v;
  if (t == 255) off[NN] = s[255];
}

__global__ __launch_bounds__(256) void scanC_k(int* __restrict__ off,
    const int* __restrict__ tbase) {
  int idx = blockIdx.x * 256 + threadIdx.x;
  if (idx < NN) off[idx] += tbase[blockIdx.x];
}

// ---- CSR build: scatter (src|type packed) -------------------------------
__global__ void scatter_k(const int* __restrict__ ei, const int* __restrict__ et,
                          const int* __restrict__ off, int* __restrict__ fill,
                          int* __restrict__ sorted) {
  int e = blockIdx.x * blockDim.x + threadIdx.x;
  if (e >= EE) return;
  int src = ei[e], dst = ei[EE + e], t = et[e];
  int pos = off[dst] + atomicAdd(&fill[dst], 1);
  sorted[pos] = src | (t << 20);
}

// ---- fused per-dst with cooperative block-level gather into LDS ----------
#define RPN 16    // edges per node per round
#define CAPE 256  // max edges per block window

__global__ __launch_bounds__(256) void dst_k(const int* __restrict__ sorted,
    const int* __restrict__ off, float* __restrict__ Y,
    const __hip_bfloat16* __restrict__ XG,
    const float* __restrict__ as_, const float* __restrict__ ad_,
    const float* __restrict__ gat_b, const int* __restrict__ gb,
    int* __restrict__ gstart, int* __restrict__ gend) {
  __shared__ int   s_pk[CAPE];
  __shared__ float s_as[CAPE];
  __shared__ __align__(16) __hip_bfloat16 s_rows[64][2][64];  // 16 KB
  __shared__ int s_b[4], s_deg[4];

  int tid = threadIdx.x;
  int wid = tid >> 6, h = tid & 63;
  int n0 = blockIdx.x * 4;
  int n = n0 + wid;                      // always < NN (50000 = 12500*4)

  int o0 = off[n0];
  int T = off[n0 + 4] - o0; if (T > CAPE) T = CAPE;

  if (tid < T) {
    int pk = sorted[o0 + tid];
    s_pk[tid] = pk;
    int s = pk & 0xFFFFF; if (s >= NN) s = NN - 1;
    s_as[tid] = as_[s];
  }
  if (h == 0) {
    int on = off[n], on1 = off[n + 1];
    int b = on - o0, d = on1 - on;
    if (b > CAPE) b = CAPE;
    if (b + d > CAPE) d = CAPE - b;
    s_b[wid] = b; s_deg[wid] = d;
  }
  __syncthreads();

  int myb = s_b[wid], mydeg = s_deg[wid];
  int dmax = max(max(s_deg[0], s_deg[1]), max(s_deg[2], s_deg[3]));
  int rounds = (dmax + RPN - 1) / RPN;

  float* yd = Y + (size_t)n * 832;
  float b0 = yd[384 + h], g0 = yd[448 + h];
  float b1 = yd[512 + h], g1 = yd[576 + h];
  float b2 = yd[640 + h], g2 = yd[704 + h];
  float adn = ad_[n];
  float m = leaky02(as_[n] + adn);
  float den = 1.f;
  float S = yd[768 + h];
  float f0 = 0.f, f1 = 0.f, f2 = 0.f;
  int c0 = 0, c1 = 0, c2 = 0;

  const int grp = tid >> 3, lane8 = tid & 7;

  for (int r = 0; r < rounds; r++) {
    int e0 = r * RPN;
    #pragma unroll
    for (int k = 0; k < 4; k++) {
      int ri = grp + 32 * k;
      int slot = ri & 63;
      int part = ri >> 6;
      int wd = slot >> 4, j = slot & 15;
      int jj = e0 + j;
      if (jj < s_deg[wd]) {
        int be = (s_b[wd] + jj) & (CAPE - 1);
        int pk = s_pk[be];
        int src = pk & 0xFFFFF; if (src >= NN) src = NN - 1;
        int t = pk >> 20;
        const __hip_bfloat16* row = XG + (size_t)src * 256
                                  + (part ? (64 + (t << 6)) : 0);
        uint4 v = *reinterpret_cast<const uint4*>(row + lane8 * 8);
        *reinterpret_cast<uint4*>(&s_rows[slot][part][lane8 * 8]) = v;
      }
    }
    __syncthreads();
    int cn = mydeg - e0; if (cn > RPN) cn = RPN;
    if (cn > 0) {
      float e = -1e30f;
      if (h < cn) e = leaky02(s_as[(myb + e0 + h) & (CAPE - 1)] + adn);
      float cm = e;
      #pragma unroll
      for (int ofs = 32; ofs > 0; ofs >>= 1) cm = fmaxf(cm, __shfl_xor(cm, ofs));
      float mn = fmaxf(m, cm);
      float w = (h < cn) ? __expf(e - mn) : 0.f;
      float ds = w;
      #pragma unroll
      for (int ofs = 32; ofs > 0; ofs >>= 1) ds += __shfl_xor(ds, ofs);
      float sc = __expf(m - mn);
      den = den * sc + ds;
      S *= sc;
      m = mn;
      for (int j = 0; j < cn; j++) {
        float wj = __shfl(w, j);
        int pkj = s_pk[(myb + e0 + j) & (CAPE - 1)];
        int tj = pkj >> 20;
        int slot = wid * RPN + j;
        float xp = __bfloat162float(s_rows[slot][0][h]);
        float xr = __bfloat162float(s_rows[slot][1][h]);
        S += wj * xp;
        float gt = tj == 0 ? g0 : (tj == 1 ? g1 : g2);
        float bt = tj == 0 ? b0 : (tj == 1 ? b1 : b2);
        float msg = fmaxf(gt * xr + bt, 0.f);
        if (tj == 0)      { f0 += msg; c0++; }
        else if (tj == 1) { f1 += msg; c1++; }
        else              { f2 += msg; c2++; }
      }
    }
    __syncthreads();
  }

  float agg = f0 / (float)(c0 > 1 ? c0 : 1)
            + f1 / (float)(c1 > 1 ? c1 : 1)
            + f2 / (float)(c2 > 1 ? c2 : 1);
  float o1 = fmaxf(yd[h] + agg, 0.f);
  float o2 = fmaxf(S / den + gat_b[h], 0.f);
  yd[192 + h] = o1;
  yd[256 + h] = o2;
  if (h == 0) {
    int g = gb[n];
    if (n == 0 || gb[n - 1] != g)      gstart[g] = n;
    if (n == NN - 1 || gb[n + 1] != g) gend[g] = n;
  }
}

// ---- parallel pooling: 8 chunks per graph, atomic max/sum ---------------
__global__ __launch_bounds__(128) void pool_k(const float* __restrict__ Y,
    const int* __restrict__ gstart, const int* __restrict__ gend,
    float* __restrict__ pmax, float* __restrict__ psum) {
  int g = blockIdx.x, chunk = blockIdx.y, f = threadIdx.x;
  int s = gstart[g], e = gend[g];
  if (s > e || s >= NN || s < 0) return;
  if (e >= NN) e = NN - 1;
  int len = e - s + 1;
  int per = (len + 7) >> 3;
  int a = s + chunk * per;
  int bnd = a + per; if (bnd > e + 1) bnd = e + 1;
  if (a >= bnd) return;
  float mx = 0.f, sm = 0.f;
  for (int n = a; n < bnd; n++) {
    float v = Y[(size_t)n * 832 + 192 + f];
    mx = fmaxf(mx, v);
    sm += v;
  }
  atomicMaxFPos(&pmax[g * 128 + f], mx);
  atomicAdd(&psum[g * 128 + f], sm);
}

// ---- head MLP + log_softmax (fp32 out) ----------------------------------
__global__ __launch_bounds__(64) void head_k(const float* __restrict__ pmax,
    const float* __restrict__ psum, const int* __restrict__ gstart,
    const int* __restrict__ gend,
    const float* __restrict__ lin_W, const float* __restrict__ lin_b,
    const float* __restrict__ fc_W, const float* __restrict__ fc_b,
    float* __restrict__ out) {
  __shared__ float p[256];
  __shared__ float hid[64];
  __shared__ float lg[CC];
  __shared__ float lse;
  int g = blockIdx.x, t = threadIdx.x;
  int s = gstart[g], e = gend[g];
  int cnt = (s <= e && s < NN && s >= 0) ? (e - s + 1) : 0;
  float invc = 1.f / (float)(cnt > 1 ? cnt : 1);
  for (int i = t; i < 256; i += 64)
    p[i] = (i < 128) ? pmax[g * 128 + i] : psum[g * 128 + (i - 128)] * invc;
  __syncthreads();
  float acc = lin_b[t];
  for (int k = 0; k < 256; k++) acc += p[k] * lin_W[k * 64 + t];
  hid[t] = fmaxf(acc, 0.f);
  __syncthreads();
  if (t < CC) {
    float a = fc_b[t];
    for (int k = 0; k < 64; k++) a += hid[k] * fc_W[k * CC + t];
    lg[t] = a;
  }
  __syncthreads();
  if (t == 0) {
    float mx = lg[0];
    for (int i = 1; i < CC; i++) mx = fmaxf(mx, lg[i]);
    float sum = 0.f;
    for (int i = 0; i < CC; i++) sum += expf(lg[i] - mx);
    lse = mx + logf(sum);
  }
  __syncthreads();
  if (t < CC) out[g * CC + t] = lg[t] - lse;
}

extern "C" void kernel_launch(void* const* d_in, const int* in_sizes, int n_in,
                              void* d_out, int out_size, void* d_ws, size_t ws_size,
                              hipStream_t stream) {
  const float* x            = (const float*)d_in[0];
  const int*   edge_index   = (const int*)d_in[1];
  const int*   edge_type    = (const int*)d_in[2];
  const int*   graph_batch  = (const int*)d_in[3];
  const float* film_lin_W   = (const float*)d_in[4];
  const float* film_film_W  = (const float*)d_in[5];
  const float* film_film_b  = (const float*)d_in[6];
  const float* skip_W       = (const float*)d_in[7];
  const float* skip_film_W  = (const float*)d_in[8];
  const float* skip_film_b  = (const float*)d_in[9];
  const float* gat_W        = (const float*)d_in[10];
  const float* att_src      = (const float*)d_in[11];
  const float* att_dst      = (const float*)d_in[12];
  const float* gat_b        = (const float*)d_in[13];
  const float* lin_W        = (const float*)d_in[14];
  const float* lin_b        = (const float*)d_in[15];
  const float* fc_W         = (const float*)d_in[16];
  const float* fc_b         = (const float*)d_in[17];
  float* out                = (float*)d_out;

  float* ws = (float*)d_ws;
  const size_t N = NN, E = EE, G = GG;
  size_t oY      = 0;                       // N*832
  size_t oXG     = N * 832;                 // N*128 float slots (N*256 bf16)
  size_t oAs     = oXG + N * 128;           // N
  size_t oAd     = oAs + N;                 // N
  size_t oXbf    = oAd + N;                 // N*32 float slots (N*64 shorts)
  size_t oWt     = oXbf + N * 32;           // 832*64 shorts = 26624 fl slots
  size_t oBias   = oWt + 832 * 32;          // 832
  size_t oPmax   = oBias + 832;             // G*128 } zero region
  size_t oPsum   = oPmax + G * 128;         // G*128 }
  size_t oGend   = oPsum + G * 128;         // G     }
  size_t oDeg    = oGend + G;               // N     }
  size_t oFill   = oDeg + N;                // N     }
  size_t oGstart = oFill + N;               // G (0x7f)
  size_t oOff    = oGstart + G;             // N+1
  size_t oTsum   = oOff + N + 1;            // 256
  size_t oTbase  = oTsum + 256;             // 256
  size_t oSorted = oTbase + 256;            // E

  float* Y      = ws + oY;
  __hip_bfloat16* XG = (__hip_bfloat16*)(ws + oXG);
  float* as_    = ws + oAs;
  float* ad_    = ws + oAd;
  unsigned short* Xbf = (unsigned short*)(ws + oXbf);
  unsigned short* Wt  = (unsigned short*)(ws + oWt);
  float* bias   = ws + oBias;
  float* pmax   = ws + oPmax;
  float* psum   = ws + oPsum;
  int*   gend   = (int*)(ws + oGend);
  int*   deg    = (int*)(ws + oDeg);
  int*   fill   = (int*)(ws + oFill);
  int*   gstart = (int*)(ws + oGstart);
  int*   off    = (int*)(ws + oOff);
  int*   tsum   = (int*)(ws + oTsum);
  int*   tbase  = (int*)(ws + oTbase);
  int*   sorted = (int*)(ws + oSorted);

  size_t zeroFloats = oGstart - oPmax;   // pmax,psum,gend,deg,fill
  hipMemsetAsync(pmax, 0, zeroFloats * sizeof(float), stream);
  hipMemsetAsync(gstart, 0x7f, G * sizeof(int), stream);

  pack_w_k<<<(832 * 64 + 832 + 255) / 256, 256, 0, stream>>>(
      skip_film_W, skip_W, film_lin_W, film_film_W, gat_W,
      skip_film_b, film_film_b, Wt, bias);
  xcvt_k<<<(NN * 64 / 4 + 255) / 256, 256, 0, stream>>>(x, Xbf);
  gemm_k<<<dim3((NN + 63) / 64, 7), 256, 0, stream>>>(Xbf, Wt, bias, Y);
  post_k<<<(NN + 3) / 4, 256, 0, stream>>>(Y, att_src, att_dst, as_, ad_, XG);
  count_k<<<(EE + 255) / 256, 256, 0, stream>>>(edge_index, deg);
  scanA_k<<<NT, 256, 0, stream>>>(deg, off, tsum);
  scanB_k<<<1, 256, 0, stream>>>(tsum, tbase, off);
  scanC_k<<<NT, 256, 0, stream>>>(off, tbase);
  scatter_k<<<(EE + 255) / 256, 256, 0, stream>>>(edge_index, edge_type,
                                                  off, fill, sorted);
  dst_k<<<NN / 4, 256, 0, stream>>>(sorted, off, Y, XG, as_, ad_,
                                    gat_b, graph_batch, gstart, gend);
  pool_k<<<dim3(GG, 8), 128, 0, stream>>>(Y, gstart, gend, pmax, psum);
  head_k<<<GG, 64, 0, stream>>>(pmax, psum, gstart, gend,
                                lin_W, lin_b, fc_W, fc_b, out);
}

// Round 10
// 344.939 us; speedup vs baseline: 2.6322x; 1.0509x over previous
//
#include <hip/hip_runtime.h>
#include <hip/hip_bf16.h>

// Problem constants (from reference)
#define NN 50000
#define EE 800000
#define GG 64
#define RR 3
#define CC 10
// Yb bf16 per node (832 cols): [0:128 fs | 128:192 xs | 192:384 xr(r=0..2) |
//                               384:768 fm(r, beta|gamma) | 768:832 xp]
// gemm writes Yb directly in bf16 (+bias). Yb IS the gather table:
// xp @ col 768, xr_t @ col 192+64t. post_k: skip_out f32 -> S0, att scalars.
// dst_k: gathers Yb rows, feats -> dense F[n][128] f32. Graph boundaries by
// sorted-gb neighbor compare (NO atomics: 64-addr atomics serialized ~350us).

typedef __attribute__((ext_vector_type(8))) short bf16x8;
typedef __attribute__((ext_vector_type(4))) float f32x4;

__device__ inline float leaky02(float x) { return x > 0.f ? x : 0.2f * x; }

// valid for non-negative floats only (int compare == float compare there)
__device__ inline void atomicMaxFPos(float* addr, float v) {
  atomicMax((int*)addr, __float_as_int(v));
}

__device__ inline unsigned short f2bf(float f) {
  __hip_bfloat16 b = __float2bfloat16(f);
  return *reinterpret_cast<unsigned short*>(&b);
}
__device__ inline float bf2f(unsigned short u) {
  return __uint_as_float(((unsigned int)u) << 16);   // exact widening
}

// ---- pack node weights into Wt bf16 [832][64] + bias vec (832) ----------
__global__ void pack_w_k(const float* __restrict__ skip_film_W,
                         const float* __restrict__ skip_W,
                         const float* __restrict__ film_lin_W,
                         const float* __restrict__ film_film_W,
                         const float* __restrict__ gat_W,
                         const float* __restrict__ skip_film_b,
                         const float* __restrict__ film_film_b,
                         unsigned short* __restrict__ Wt,
                         float* __restrict__ bias) {
  int idx = blockIdx.x * blockDim.x + threadIdx.x;
  if (idx >= 832 * 64 + 832) return;
  if (idx >= 832 * 64) {
    int c = idx - 832 * 64;
    float b = 0.f;
    if (c < 128) b = skip_film_b[c];
    else if (c >= 384 && c < 768) b = film_film_b[c - 384];
    bias[c] = b;
    return;
  }
  int c = idx >> 6, k = idx & 63;      // Wt[c][k] = Wcat[k][c]
  float v;
  if (c < 128)      v = skip_film_W[k * 128 + c];
  else if (c < 192) v = skip_W[k * 64 + (c - 128)];
  else if (c < 384) { int cc = c - 192, r = cc >> 6, h = cc & 63;
                      v = film_lin_W[(r * 64 + k) * 64 + h]; }
  else if (c < 768) { int cc = c - 384, r = cc >> 7, j = cc & 127;
                      v = film_film_W[(r * 64 + k) * 128 + j]; }
  else              v = gat_W[k * 64 + (c - 768)];
  Wt[idx] = f2bf(v);
}

// ---- X fp32 -> bf16 ------------------------------------------------------
__global__ void xcvt_k(const float* __restrict__ X,
                       unsigned short* __restrict__ Xbf) {
  int i = blockIdx.x * blockDim.x + threadIdx.x;
  int idx = i * 4;
  if (idx >= NN * 64) return;
  float4 v = *reinterpret_cast<const float4*>(X + idx);
  ushort4 o = {f2bf(v.x), f2bf(v.y), f2bf(v.z), f2bf(v.w)};
  *reinterpret_cast<ushort4*>(Xbf + idx) = o;
}

// ---- MFMA GEMM: Xbf(50000x64) @ Wt^T(64x832) + bias -> Yb bf16 ----------
__global__ __launch_bounds__(256) void gemm_k(const unsigned short* __restrict__ Xbf,
                                              const unsigned short* __restrict__ Wt,
                                              const float* __restrict__ bias,
                                              unsigned short* __restrict__ Yb) {
  __shared__ __align__(16) unsigned short As[64][72];
  __shared__ __align__(16) unsigned short Bs[128][72];
  const int tid = threadIdx.x;
  const int row0 = blockIdx.x * 64;
  const int col0 = blockIdx.y * 128;

  // A: 16 shorts/thread (2x uint4)
  {
    int r = tid >> 2, c0 = (tid & 3) * 16;
    int gr = row0 + r;
    uint4 v0 = {0, 0, 0, 0}, v1 = {0, 0, 0, 0};
    if (gr < NN) {
      const uint4* p = reinterpret_cast<const uint4*>(Xbf + (size_t)gr * 64 + c0);
      v0 = p[0]; v1 = p[1];
    }
    *reinterpret_cast<uint4*>(&As[r][c0])     = v0;
    *reinterpret_cast<uint4*>(&As[r][c0 + 8]) = v1;
  }
  // B: 32 shorts/thread (4x uint4); Wt is [col][k] so rows are contiguous
  {
    int c = tid >> 1, half = (tid & 1) * 32;
    int gc = col0 + c;
    uint4 v0 = {0,0,0,0}, v1 = {0,0,0,0}, v2 = {0,0,0,0}, v3 = {0,0,0,0};
    if (gc < 832) {
      const uint4* p = reinterpret_cast<const uint4*>(Wt + (size_t)gc * 64 + half);
      v0 = p[0]; v1 = p[1]; v2 = p[2]; v3 = p[3];
    }
    *reinterpret_cast<uint4*>(&Bs[c][half])      = v0;
    *reinterpret_cast<uint4*>(&Bs[c][half + 8])  = v1;
    *reinterpret_cast<uint4*>(&Bs[c][half + 16]) = v2;
    *reinterpret_cast<uint4*>(&Bs[c][half + 24]) = v3;
  }
  __syncthreads();

  const int w = tid >> 6, lane = tid & 63;
  const int m = lane & 15, q = lane >> 4;
  bf16x8 a0 = *reinterpret_cast<const bf16x8*>(&As[16 * w + m][q * 8]);
  bf16x8 a1 = *reinterpret_cast<const bf16x8*>(&As[16 * w + m][32 + q * 8]);
  int rbase = row0 + 16 * w + q * 4;

  for (int ct = 0; ct < 8; ct++) {
    if (col0 + ct * 16 >= 832) break;          // wave-uniform
    bf16x8 b0 = *reinterpret_cast<const bf16x8*>(&Bs[ct * 16 + m][q * 8]);
    bf16x8 b1 = *reinterpret_cast<const bf16x8*>(&Bs[ct * 16 + m][32 + q * 8]);
    f32x4 acc = {0.f, 0.f, 0.f, 0.f};
    acc = __builtin_amdgcn_mfma_f32_16x16x32_bf16(a0, b0, acc, 0, 0, 0);
    acc = __builtin_amdgcn_mfma_f32_16x16x32_bf16(a1, b1, acc, 0, 0, 0);
    int gc = col0 + ct * 16 + m;               // C/D: col=lane&15
    float bv = bias[gc];
    #pragma unroll
    for (int rg = 0; rg < 4; rg++) {           // C/D: row=q*4+reg
      int gr = rbase + rg;
      if (gr < NN) Yb[(size_t)gr * 832 + gc] = f2bf(acc[rg] + bv);
    }
  }
}

// ---- per-node post: skip_out f32, attention scalars ---------------------
__global__ __launch_bounds__(256) void post_k(const unsigned short* __restrict__ Yb,
    const float* __restrict__ att_src, const float* __restrict__ att_dst,
    float* __restrict__ as_, float* __restrict__ ad_,
    float* __restrict__ S0) {
  int n = blockIdx.x * 4 + (threadIdx.x >> 6);
  if (n >= NN) return;
  int h = threadIdx.x & 63;
  const unsigned short* y = Yb + (size_t)n * 832;
  float fsb = bf2f(y[h]);
  float fsg = bf2f(y[64 + h]);
  float xs  = bf2f(y[128 + h]);
  float xph = bf2f(y[768 + h]);
  S0[(size_t)n * 64 + h] = fmaxf(fsg * xs + fsb, 0.f);
  float pa = xph * att_src[h], pd = xph * att_dst[h];
  #pragma unroll
  for (int off = 32; off > 0; off >>= 1) {
    pa += __shfl_xor(pa, off);
    pd += __shfl_xor(pd, off);
  }
  if (h == 0) { as_[n] = pa; ad_[n] = pd; }
}

// ---- CSR build: count ----------------------------------------------------
__global__ void count_k(const int* __restrict__ ei, int* __restrict__ deg) {
  int e = blockIdx.x * blockDim.x + threadIdx.x;
  if (e >= EE) return;
  atomicAdd(&deg[ei[EE + e]], 1);
}

// ---- 3-phase parallel exclusive scan ------------------------------------
#define NT 196   // ceil(50000/256)
__global__ __launch_bounds__(256) void scanA_k(const int* __restrict__ deg,
    int* __restrict__ off, int* __restrict__ tsum) {
  __shared__ int s[256];
  int t = threadIdx.x, idx = blockIdx.x * 256 + t;
  int v = (idx < NN) ? deg[idx] : 0;
  s[t] = v;
  __syncthreads();
  for (int ofs = 1; ofs < 256; ofs <<= 1) {
    int u = (t >= ofs) ? s[t - ofs] : 0;
    __syncthreads();
    s[t] += u;
    __syncthreads();
  }
  if (idx < NN) off[idx] = s[t] - v;
  if (t == 255) tsum[blockIdx.x] = s[255];
}

__global__ __launch_bounds__(256) void scanB_k(const int* __restrict__ tsum,
    int* __restrict__ tbase, int* __restrict__ off) {
  __shared__ int s[256];
  int t = threadIdx.x;
  int v = (t < NT) ? tsum[t] : 0;
  s[t] = v;
  __syncthreads();
  for (int ofs = 1; ofs < 256; ofs <<= 1) {
    int u = (t >= ofs) ? s[t - ofs] : 0;
    __syncthreads();
    s[t] += u;
    __syncthreads();
  }
  if (t < NT) tbase[t] = s[t] - v;
  if (t == 255) off[NN] = s[255];
}

__global__ __launch_bounds__(256) void scanC_k(int* __restrict__ off,
    const int* __restrict__ tbase) {
  int idx = blockIdx.x * 256 + threadIdx.x;
  if (idx < NN) off[idx] += tbase[blockIdx.x];
}

// ---- CSR build: scatter (src|type packed) -------------------------------
__global__ void scatter_k(const int* __restrict__ ei, const int* __restrict__ et,
                          const int* __restrict__ off, int* __restrict__ fill,
                          int* __restrict__ sorted) {
  int e = blockIdx.x * blockDim.x + threadIdx.x;
  if (e >= EE) return;
  int src = ei[e], dst = ei[EE + e], t = et[e];
  int pos = off[dst] + atomicAdd(&fill[dst], 1);
  sorted[pos] = src | (t << 20);
}

// ---- fused per-dst with cooperative block-level gather into LDS ----------
#define RPN 16    // edges per node per round
#define CAPE 256  // max edges per block window

__global__ __launch_bounds__(256) void dst_k(const int* __restrict__ sorted,
    const int* __restrict__ off, const unsigned short* __restrict__ Yb,
    const float* __restrict__ S0,
    const float* __restrict__ as_, const float* __restrict__ ad_,
    const float* __restrict__ gat_b, const int* __restrict__ gb,
    float* __restrict__ F, int* __restrict__ gstart, int* __restrict__ gend) {
  __shared__ int   s_pk[CAPE];
  __shared__ float s_as[CAPE];
  __shared__ __align__(16) unsigned short s_rows[64][2][64];  // 16 KB
  __shared__ int s_b[4], s_deg[4];

  int tid = threadIdx.x;
  int wid = tid >> 6, h = tid & 63;
  int n0 = blockIdx.x * 4;
  int n = n0 + wid;                      // always < NN (50000 = 12500*4)

  int o0 = off[n0];
  int T = off[n0 + 4] - o0; if (T > CAPE) T = CAPE;

  if (tid < T) {
    int pk = sorted[o0 + tid];
    s_pk[tid] = pk;
    int s = pk & 0xFFFFF; if (s >= NN) s = NN - 1;
    s_as[tid] = as_[s];
  }
  if (h == 0) {
    int on = off[n], on1 = off[n + 1];
    int b = on - o0, d = on1 - on;
    if (b > CAPE) b = CAPE;
    if (b + d > CAPE) d = CAPE - b;
    s_b[wid] = b; s_deg[wid] = d;
  }
  __syncthreads();

  int myb = s_b[wid], mydeg = s_deg[wid];
  int dmax = max(max(s_deg[0], s_deg[1]), max(s_deg[2], s_deg[3]));
  int rounds = (dmax + RPN - 1) / RPN;

  const unsigned short* yd = Yb + (size_t)n * 832;
  float b0 = bf2f(yd[384 + h]), g0 = bf2f(yd[448 + h]);
  float b1 = bf2f(yd[512 + h]), g1 = bf2f(yd[576 + h]);
  float b2 = bf2f(yd[640 + h]), g2 = bf2f(yd[704 + h]);
  float adn = ad_[n];
  float m = leaky02(as_[n] + adn);
  float den = 1.f;
  float S = bf2f(yd[768 + h]);         // self xp
  float f0 = 0.f, f1 = 0.f, f2 = 0.f;
  int c0 = 0, c1 = 0, c2 = 0;

  const int grp = tid >> 3, lane8 = tid & 7;

  for (int r = 0; r < rounds; r++) {
    int e0 = r * RPN;
    #pragma unroll
    for (int k = 0; k < 4; k++) {
      int ri = grp + 32 * k;
      int slot = ri & 63;
      int part = ri >> 6;               // 0 = xp(col768), 1 = xr_t(col192+64t)
      int wd = slot >> 4, j = slot & 15;
      int jj = e0 + j;
      if (jj < s_deg[wd]) {
        int be = (s_b[wd] + jj) & (CAPE - 1);
        int pk = s_pk[be];
        int src = pk & 0xFFFFF; if (src >= NN) src = NN - 1;
        int t = pk >> 20;
        const unsigned short* row = Yb + (size_t)src * 832
                                  + (part ? (192 + (t << 6)) : 768);
        uint4 v = *reinterpret_cast<const uint4*>(row + lane8 * 8);
        *reinterpret_cast<uint4*>(&s_rows[slot][part][lane8 * 8]) = v;
      }
    }
    __syncthreads();
    int cn = mydeg - e0; if (cn > RPN) cn = RPN;
    if (cn > 0) {
      float e = -1e30f;
      if (h < cn) e = leaky02(s_as[(myb + e0 + h) & (CAPE - 1)] + adn);
      float cm = e;
      #pragma unroll
      for (int ofs = 32; ofs > 0; ofs >>= 1) cm = fmaxf(cm, __shfl_xor(cm, ofs));
      float mn = fmaxf(m, cm);
      float w = (h < cn) ? __expf(e - mn) : 0.f;
      float ds = w;
      #pragma unroll
      for (int ofs = 32; ofs > 0; ofs >>= 1) ds += __shfl_xor(ds, ofs);
      float sc = __expf(m - mn);
      den = den * sc + ds;
      S *= sc;
      m = mn;
      for (int j = 0; j < cn; j++) {
        float wj = __shfl(w, j);
        int pkj = s_pk[(myb + e0 + j) & (CAPE - 1)];
        int tj = pkj >> 20;
        int slot = wid * RPN + j;
        float xp = bf2f(s_rows[slot][0][h]);
        float xr = bf2f(s_rows[slot][1][h]);
        S += wj * xp;
        float gt = tj == 0 ? g0 : (tj == 1 ? g1 : g2);
        float bt = tj == 0 ? b0 : (tj == 1 ? b1 : b2);
        float msg = fmaxf(gt * xr + bt, 0.f);
        if (tj == 0)      { f0 += msg; c0++; }
        else if (tj == 1) { f1 += msg; c1++; }
        else              { f2 += msg; c2++; }
      }
    }
    __syncthreads();
  }

  float agg = f0 / (float)(c0 > 1 ? c0 : 1)
            + f1 / (float)(c1 > 1 ? c1 : 1)
            + f2 / (float)(c2 > 1 ? c2 : 1);
  float o1 = fmaxf(S0[(size_t)n * 64 + h] + agg, 0.f);
  float o2 = fmaxf(S / den + gat_b[h], 0.f);
  F[(size_t)n * 128 + h]      = o1;
  F[(size_t)n * 128 + 64 + h] = o2;
  if (h == 0) {
    int g = gb[n];
    if (n == 0 || gb[n - 1] != g)      gstart[g] = n;
    if (n == NN - 1 || gb[n + 1] != g) gend[g] = n;
  }
}

// ---- parallel pooling: 8 chunks per graph, atomic max/sum ---------------
__global__ __launch_bounds__(128) void pool_k(const float* __restrict__ F,
    const int* __restrict__ gstart, const int* __restrict__ gend,
    float* __restrict__ pmax, float* __restrict__ psum) {
  int g = blockIdx.x, chunk = blockIdx.y, f = threadIdx.x;
  int s = gstart[g], e = gend[g];
  if (s > e || s >= NN || s < 0) return;
  if (e >= NN) e = NN - 1;
  int len = e - s + 1;
  int per = (len + 7) >> 3;
  int a = s + chunk * per;
  int bnd = a + per; if (bnd > e + 1) bnd = e + 1;
  if (a >= bnd) return;
  float mx = 0.f, sm = 0.f;          // feats >= 0 (both relu'd)
  for (int n = a; n < bnd; n++) {
    float v = F[(size_t)n * 128 + f];
    mx = fmaxf(mx, v);
    sm += v;
  }
  atomicMaxFPos(&pmax[g * 128 + f], mx);
  atomicAdd(&psum[g * 128 + f], sm);
}

// ---- head MLP + log_softmax (fp32 out) ----------------------------------
__global__ __launch_bounds__(64) void head_k(const float* __restrict__ pmax,
    const float* __restrict__ psum, const int* __restrict__ gstart,
    const int* __restrict__ gend,
    const float* __restrict__ lin_W, const float* __restrict__ lin_b,
    const float* __restrict__ fc_W, const float* __restrict__ fc_b,
    float* __restrict__ out) {
  __shared__ float p[256];
  __shared__ float hid[64];
  __shared__ float lg[CC];
  __shared__ float lse;
  int g = blockIdx.x, t = threadIdx.x;
  int s = gstart[g], e = gend[g];
  int cnt = (s <= e && s < NN && s >= 0) ? (e - s + 1) : 0;
  float invc = 1.f / (float)(cnt > 1 ? cnt : 1);
  for (int i = t; i < 256; i += 64)
    p[i] = (i < 128) ? pmax[g * 128 + i] : psum[g * 128 + (i - 128)] * invc;
  __syncthreads();
  float acc = lin_b[t];
  for (int k = 0; k < 256; k++) acc += p[k] * lin_W[k * 64 + t];
  hid[t] = fmaxf(acc, 0.f);
  __syncthreads();
  if (t < CC) {
    float a = fc_b[t];
    for (int k = 0; k < 64; k++) a += hid[k] * fc_W[k * CC + t];
    lg[t] = a;
  }
  __syncthreads();
  if (t == 0) {
    float mx = lg[0];
    for (int i = 1; i < CC; i++) mx = fmaxf(mx, lg[i]);
    float sum = 0.f;
    for (int i = 0; i < CC; i++) sum += expf(lg[i] - mx);
    lse = mx + logf(sum);
  }
  __syncthreads();
  if (t < CC) out[g * CC + t] = lg[t] - lse;
}

extern "C" void kernel_launch(void* const* d_in, const int* in_sizes, int n_in,
                              void* d_out, int out_size, void* d_ws, size_t ws_size,
                              hipStream_t stream) {
  const float* x            = (const float*)d_in[0];
  const int*   edge_index   = (const int*)d_in[1];
  const int*   edge_type    = (const int*)d_in[2];
  const int*   graph_batch  = (const int*)d_in[3];
  const float* film_lin_W   = (const float*)d_in[4];
  const float* film_film_W  = (const float*)d_in[5];
  const float* film_film_b  = (const float*)d_in[6];
  const float* skip_W       = (const float*)d_in[7];
  const float* skip_film_W  = (const float*)d_in[8];
  const float* skip_film_b  = (const float*)d_in[9];
  const float* gat_W        = (const float*)d_in[10];
  const float* att_src      = (const float*)d_in[11];
  const float* att_dst      = (const float*)d_in[12];
  const float* gat_b        = (const float*)d_in[13];
  const float* lin_W        = (const float*)d_in[14];
  const float* lin_b        = (const float*)d_in[15];
  const float* fc_W         = (const float*)d_in[16];
  const float* fc_b         = (const float*)d_in[17];
  float* out                = (float*)d_out;

  float* ws = (float*)d_ws;
  const size_t N = NN, E = EE, G = GG;
  size_t oYb     = 0;                       // N*416 fl slots (N*832 bf16)
  size_t oF      = N * 416;                 // N*128 f32
  size_t oS0     = oF + N * 128;            // N*64 f32
  size_t oAs     = oS0 + N * 64;            // N
  size_t oAd     = oAs + N;                 // N
  size_t oXbf    = oAd + N;                 // N*32 fl slots (N*64 shorts)
  size_t oWt     = oXbf + N * 32;           // 832*32 fl slots
  size_t oBias   = oWt + 832 * 32;          // 832
  size_t oPmax   = oBias + 832;             // G*128 } zero region
  size_t oPsum   = oPmax + G * 128;         // G*128 }
  size_t oGend   = oPsum + G * 128;         // G     }
  size_t oDeg    = oGend + G;               // N     }
  size_t oFill   = oDeg + N;                // N     }
  size_t oGstart = oFill + N;               // G (0x7f)
  size_t oOff    = oGstart + G;             // N+1
  size_t oTsum   = oOff + N + 1;            // 256
  size_t oTbase  = oTsum + 256;             // 256
  size_t oSorted = oTbase + 256;            // E

  unsigned short* Yb  = (unsigned short*)(ws + oYb);
  float* F      = ws + oF;
  float* S0     = ws + oS0;
  float* as_    = ws + oAs;
  float* ad_    = ws + oAd;
  unsigned short* Xbf = (unsigned short*)(ws + oXbf);
  unsigned short* Wt  = (unsigned short*)(ws + oWt);
  float* bias   = ws + oBias;
  float* pmax   = ws + oPmax;
  float* psum   = ws + oPsum;
  int*   gend   = (int*)(ws + oGend);
  int*   deg    = (int*)(ws + oDeg);
  int*   fill   = (int*)(ws + oFill);
  int*   gstart = (int*)(ws + oGstart);
  int*   off    = (int*)(ws + oOff);
  int*   tsum   = (int*)(ws + oTsum);
  int*   tbase  = (int*)(ws + oTbase);
  int*   sorted = (int*)(ws + oSorted);

  size_t zeroFloats = oGstart - oPmax;   // pmax,psum,gend,deg,fill
  hipMemsetAsync(pmax, 0, zeroFloats * sizeof(float), stream);
  hipMemsetAsync(gstart, 0x7f, G * sizeof(int), stream);

  pack_w_k<<<(832 * 64 + 832 + 255) / 256, 256, 0, stream>>>(
      skip_film_W, skip_W, film_lin_W, film_film_W, gat_W,
      skip_film_b, film_film_b, Wt, bias);
  xcvt_k<<<(NN * 64 / 4 + 255) / 256, 256, 0, stream>>>(x, Xbf);
  gemm_k<<<dim3((NN + 63) / 64, 7), 256, 0, stream>>>(Xbf, Wt, bias, Yb);
  post_k<<<(NN + 3) / 4, 256, 0, stream>>>(Yb, att_src, att_dst, as_, ad_, S0);
  count_k<<<(EE + 255) / 256, 256, 0, stream>>>(edge_index, deg);
  scanA_k<<<NT, 256, 0, stream>>>(deg, off, tsum);
  scanB_k<<<1, 256, 0, stream>>>(tsum, tbase, off);
  scanC_k<<<NT, 256, 0, stream>>>(off, tbase);
  scatter_k<<<(EE + 255) / 256, 256, 0, stream>>>(edge_index, edge_type,
                                                  off, fill, sorted);
  dst_k<<<NN / 4, 256, 0, stream>>>(sorted, off, Yb, S0, as_, ad_,
                                    gat_b, graph_batch, F, gstart, gend);
  pool_k<<<dim3(GG, 8), 128, 0, stream>>>(F, gstart, gend, pmax, psum);
  head_k<<<GG, 64, 0, stream>>>(pmax, psum, gstart, gend,
                                lin_W, lin_b, fc_W, fc_b, out);
}

// Round 11
// 341.269 us; speedup vs baseline: 2.6605x; 1.0108x over previous
//
#include <hip/hip_runtime.h>
#include <hip/hip_bf16.h>

// Problem constants (from reference)
#define NN 50000
#define EE 800000
#define GG 64
#define RR 3
#define CC 10
// Yb bf16 per node (832 cols): [0:128 fs | 128:192 xs | 192:384 xr(r=0..2) |
//                               384:768 fm(r, beta|gamma) | 768:832 xp]
// gemm writes Yb bf16 (+bias) with LDS-staged coalesced 256B row stores.
// post_k: skip_out f32 -> S0, att scalars. dst_k: gathers Yb rows, feats ->
// dense F[n][128] f32; graph boundaries by sorted-gb neighbor compare
// (NO atomics: 64-addr atomicMin/Max serialized ~350us, rounds 3-7).

typedef __attribute__((ext_vector_type(8))) short bf16x8;
typedef __attribute__((ext_vector_type(4))) float f32x4;

__device__ inline float leaky02(float x) { return x > 0.f ? x : 0.2f * x; }

// valid for non-negative floats only (int compare == float compare there)
__device__ inline void atomicMaxFPos(float* addr, float v) {
  atomicMax((int*)addr, __float_as_int(v));
}

__device__ inline unsigned short f2bf(float f) {
  __hip_bfloat16 b = __float2bfloat16(f);
  return *reinterpret_cast<unsigned short*>(&b);
}
__device__ inline float bf2f(unsigned short u) {
  return __uint_as_float(((unsigned int)u) << 16);   // exact widening
}

// ---- fused prep: X->bf16 + deg count (blocks 0..3124), W pack (rest) ----
// NN*64/4 == EE == 800000, so one 256-thread block grid covers both.
__global__ void prep_k(const float* __restrict__ X,
                       unsigned short* __restrict__ Xbf,
                       const int* __restrict__ ei, int* __restrict__ deg,
                       const float* __restrict__ skip_film_W,
                       const float* __restrict__ skip_W,
                       const float* __restrict__ film_lin_W,
                       const float* __restrict__ film_film_W,
                       const float* __restrict__ gat_W,
                       const float* __restrict__ skip_film_b,
                       const float* __restrict__ film_film_b,
                       unsigned short* __restrict__ Wt,
                       float* __restrict__ bias) {
  int b = blockIdx.x;
  if (b < 3125) {
    int i = b * 256 + threadIdx.x;         // < 800000
    int idx = i * 4;
    float4 v = *reinterpret_cast<const float4*>(X + idx);
    ushort4 o = {f2bf(v.x), f2bf(v.y), f2bf(v.z), f2bf(v.w)};
    *reinterpret_cast<ushort4*>(Xbf + idx) = o;
    atomicAdd(&deg[ei[EE + i]], 1);
    return;
  }
  int idx = (b - 3125) * 256 + threadIdx.x;
  if (idx >= 832 * 64 + 832) return;
  if (idx >= 832 * 64) {
    int c = idx - 832 * 64;
    float bv = 0.f;
    if (c < 128) bv = skip_film_b[c];
    else if (c >= 384 && c < 768) bv = film_film_b[c - 384];
    bias[c] = bv;
    return;
  }
  int c = idx >> 6, k = idx & 63;      // Wt[c][k] = Wcat[k][c]
  float v;
  if (c < 128)      v = skip_film_W[k * 128 + c];
  else if (c < 192) v = skip_W[k * 64 + (c - 128)];
  else if (c < 384) { int cc = c - 192, r = cc >> 6, h = cc & 63;
                      v = film_lin_W[(r * 64 + k) * 64 + h]; }
  else if (c < 768) { int cc = c - 384, r = cc >> 7, j = cc & 127;
                      v = film_film_W[(r * 64 + k) * 128 + j]; }
  else              v = gat_W[k * 64 + (c - 768)];
  Wt[idx] = f2bf(v);
}

// ---- MFMA GEMM: Xbf(50000x64) @ Wt^T(64x832) + bias -> Yb bf16 ----------
// Epilogue stages C through LDS for coalesced 256B-per-row stores.
__global__ __launch_bounds__(256) void gemm_k(const unsigned short* __restrict__ Xbf,
                                              const unsigned short* __restrict__ Wt,
                                              const float* __restrict__ bias,
                                              unsigned short* __restrict__ Yb) {
  __shared__ __align__(16) unsigned short As[64][72];
  __shared__ __align__(16) unsigned short Bs[128][72];
  __shared__ __align__(16) unsigned short Cs[4][16][132];  // pad 132: low-conflict
  const int tid = threadIdx.x;
  const int row0 = blockIdx.x * 64;
  const int col0 = blockIdx.y * 128;

  // A: 16 shorts/thread (2x uint4)
  {
    int r = tid >> 2, c0 = (tid & 3) * 16;
    int gr = row0 + r;
    uint4 v0 = {0, 0, 0, 0}, v1 = {0, 0, 0, 0};
    if (gr < NN) {
      const uint4* p = reinterpret_cast<const uint4*>(Xbf + (size_t)gr * 64 + c0);
      v0 = p[0]; v1 = p[1];
    }
    *reinterpret_cast<uint4*>(&As[r][c0])     = v0;
    *reinterpret_cast<uint4*>(&As[r][c0 + 8]) = v1;
  }
  // B: 32 shorts/thread (4x uint4); Wt is [col][k] so rows are contiguous
  {
    int c = tid >> 1, half = (tid & 1) * 32;
    int gc = col0 + c;
    uint4 v0 = {0,0,0,0}, v1 = {0,0,0,0}, v2 = {0,0,0,0}, v3 = {0,0,0,0};
    if (gc < 832) {
      const uint4* p = reinterpret_cast<const uint4*>(Wt + (size_t)gc * 64 + half);
      v0 = p[0]; v1 = p[1]; v2 = p[2]; v3 = p[3];
    }
    *reinterpret_cast<uint4*>(&Bs[c][half])      = v0;
    *reinterpret_cast<uint4*>(&Bs[c][half + 8])  = v1;
    *reinterpret_cast<uint4*>(&Bs[c][half + 16]) = v2;
    *reinterpret_cast<uint4*>(&Bs[c][half + 24]) = v3;
  }
  __syncthreads();

  const int w = tid >> 6, lane = tid & 63;
  const int m = lane & 15, q = lane >> 4;
  bf16x8 a0 = *reinterpret_cast<const bf16x8*>(&As[16 * w + m][q * 8]);
  bf16x8 a1 = *reinterpret_cast<const bf16x8*>(&As[16 * w + m][32 + q * 8]);

  for (int ct = 0; ct < 8; ct++) {
    if (col0 + ct * 16 >= 832) break;          // wave-uniform
    bf16x8 b0 = *reinterpret_cast<const bf16x8*>(&Bs[ct * 16 + m][q * 8]);
    bf16x8 b1 = *reinterpret_cast<const bf16x8*>(&Bs[ct * 16 + m][32 + q * 8]);
    f32x4 acc = {0.f, 0.f, 0.f, 0.f};
    acc = __builtin_amdgcn_mfma_f32_16x16x32_bf16(a0, b0, acc, 0, 0, 0);
    acc = __builtin_amdgcn_mfma_f32_16x16x32_bf16(a1, b1, acc, 0, 0, 0);
    int gc = col0 + ct * 16 + m;               // C/D: col=lane&15
    float bv = bias[gc];
    #pragma unroll
    for (int rg = 0; rg < 4; rg++)             // C/D: row=q*4+reg
      Cs[w][q * 4 + rg][ct * 16 + m] = f2bf(acc[rg] + bv);
  }
  // wave-synchronous LDS round-trip (no barrier needed within the wave)
  int halfrow = lane >> 5;                     // 0..1
  int c4 = (lane & 31) * 4;                    // 0..124
  int gcol = col0 + c4;
  bool colok = (gcol + 3) < 832;
  #pragma unroll
  for (int step = 0; step < 8; step++) {
    int lr = step * 2 + halfrow;
    int gr = row0 + w * 16 + lr;
    if (gr < NN && colok) {
      uint2 v = *reinterpret_cast<const uint2*>(&Cs[w][lr][c4]);
      *reinterpret_cast<uint2*>(&Yb[(size_t)gr * 832 + gcol]) = v;
    }
  }
}

// ---- per-node post: skip_out f32, attention scalars ---------------------
__global__ __launch_bounds__(256) void post_k(const unsigned short* __restrict__ Yb,
    const float* __restrict__ att_src, const float* __restrict__ att_dst,
    float* __restrict__ as_, float* __restrict__ ad_,
    float* __restrict__ S0) {
  int n = blockIdx.x * 4 + (threadIdx.x >> 6);
  if (n >= NN) return;
  int h = threadIdx.x & 63;
  const unsigned short* y = Yb + (size_t)n * 832;
  float fsb = bf2f(y[h]);
  float fsg = bf2f(y[64 + h]);
  float xs  = bf2f(y[128 + h]);
  float xph = bf2f(y[768 + h]);
  S0[(size_t)n * 64 + h] = fmaxf(fsg * xs + fsb, 0.f);
  float pa = xph * att_src[h], pd = xph * att_dst[h];
  #pragma unroll
  for (int off = 32; off > 0; off >>= 1) {
    pa += __shfl_xor(pa, off);
    pd += __shfl_xor(pd, off);
  }
  if (h == 0) { as_[n] = pa; ad_[n] = pd; }
}

// ---- 3-phase parallel exclusive scan ------------------------------------
#define NT 196   // ceil(50000/256)
__global__ __launch_bounds__(256) void scanA_k(const int* __restrict__ deg,
    int* __restrict__ off, int* __restrict__ tsum) {
  __shared__ int s[256];
  int t = threadIdx.x, idx = blockIdx.x * 256 + t;
  int v = (idx < NN) ? deg[idx] : 0;
  s[t] = v;
  __syncthreads();
  for (int ofs = 1; ofs < 256; ofs <<= 1) {
    int u = (t >= ofs) ? s[t - ofs] : 0;
    __syncthreads();
    s[t] += u;
    __syncthreads();
  }
  if (idx < NN) off[idx] = s[t] - v;
  if (t == 255) tsum[blockIdx.x] = s[255];
}

__global__ __launch_bounds__(256) void scanB_k(const int* __restrict__ tsum,
    int* __restrict__ tbase, int* __restrict__ off) {
  __shared__ int s[256];
  int t = threadIdx.x;
  int v = (t < NT) ? tsum[t] : 0;
  s[t] = v;
  __syncthreads();
  for (int ofs = 1; ofs < 256; ofs <<= 1) {
    int u = (t >= ofs) ? s[t - ofs] : 0;
    __syncthreads();
    s[t] += u;
    __syncthreads();
  }
  if (t < NT) tbase[t] = s[t] - v;
  if (t == 255) off[NN] = s[255];
}

__global__ __launch_bounds__(256) void scanC_k(int* __restrict__ off,
    const int* __restrict__ tbase) {
  int idx = blockIdx.x * 256 + threadIdx.x;
  if (idx < NN) off[idx] += tbase[blockIdx.x];
}

// ---- CSR build: scatter (src|type packed) -------------------------------
__global__ void scatter_k(const int* __restrict__ ei, const int* __restrict__ et,
                          const int* __restrict__ off, int* __restrict__ fill,
                          int* __restrict__ sorted) {
  int e = blockIdx.x * blockDim.x + threadIdx.x;
  if (e >= EE) return;
  int src = ei[e], dst = ei[EE + e], t = et[e];
  int pos = off[dst] + atomicAdd(&fill[dst], 1);
  sorted[pos] = src | (t << 20);
}

// ---- fused per-dst with cooperative block-level gather into LDS ----------
#define RPN 16    // edges per node per round
#define CAPE 256  // max edges per block window

__global__ __launch_bounds__(256) void dst_k(const int* __restrict__ sorted,
    const int* __restrict__ off, const unsigned short* __restrict__ Yb,
    const float* __restrict__ S0,
    const float* __restrict__ as_, const float* __restrict__ ad_,
    const float* __restrict__ gat_b, const int* __restrict__ gb,
    float* __restrict__ F, int* __restrict__ gstart, int* __restrict__ gend) {
  __shared__ int   s_pk[CAPE];
  __shared__ float s_as[CAPE];
  __shared__ __align__(16) unsigned short s_rows[64][2][64];  // 16 KB
  __shared__ int s_b[4], s_deg[4];

  int tid = threadIdx.x;
  int wid = tid >> 6, h = tid & 63;
  int n0 = blockIdx.x * 4;
  int n = n0 + wid;                      // always < NN (50000 = 12500*4)

  int o0 = off[n0];
  int T = off[n0 + 4] - o0; if (T > CAPE) T = CAPE;

  if (tid < T) {
    int pk = sorted[o0 + tid];
    s_pk[tid] = pk;
    int s = pk & 0xFFFFF; if (s >= NN) s = NN - 1;
    s_as[tid] = as_[s];
  }
  if (h == 0) {
    int on = off[n], on1 = off[n + 1];
    int b = on - o0, d = on1 - on;
    if (b > CAPE) b = CAPE;
    if (b + d > CAPE) d = CAPE - b;
    s_b[wid] = b; s_deg[wid] = d;
  }
  __syncthreads();

  int myb = s_b[wid], mydeg = s_deg[wid];
  int dmax = max(max(s_deg[0], s_deg[1]), max(s_deg[2], s_deg[3]));
  int rounds = (dmax + RPN - 1) / RPN;

  const unsigned short* yd = Yb + (size_t)n * 832;
  float b0 = bf2f(yd[384 + h]), g0 = bf2f(yd[448 + h]);
  float b1 = bf2f(yd[512 + h]), g1 = bf2f(yd[576 + h]);
  float b2 = bf2f(yd[640 + h]), g2 = bf2f(yd[704 + h]);
  float adn = ad_[n];
  float m = leaky02(as_[n] + adn);
  float den = 1.f;
  float S = bf2f(yd[768 + h]);         // self xp
  float f0 = 0.f, f1 = 0.f, f2 = 0.f;
  int c0 = 0, c1 = 0, c2 = 0;

  const int grp = tid >> 3, lane8 = tid & 7;

  for (int r = 0; r < rounds; r++) {
    int e0 = r * RPN;
    #pragma unroll
    for (int k = 0; k < 4; k++) {
      int ri = grp + 32 * k;
      int slot = ri & 63;
      int part = ri >> 6;               // 0 = xp(col768), 1 = xr_t(col192+64t)
      int wd = slot >> 4, j = slot & 15;
      int jj = e0 + j;
      if (jj < s_deg[wd]) {
        int be = (s_b[wd] + jj) & (CAPE - 1);
        int pk = s_pk[be];
        int src = pk & 0xFFFFF; if (src >= NN) src = NN - 1;
        int t = pk >> 20;
        const unsigned short* row = Yb + (size_t)src * 832
                                  + (part ? (192 + (t << 6)) : 768);
        uint4 v = *reinterpret_cast<const uint4*>(row + lane8 * 8);
        *reinterpret_cast<uint4*>(&s_rows[slot][part][lane8 * 8]) = v;
      }
    }
    __syncthreads();
    int cn = mydeg - e0; if (cn > RPN) cn = RPN;
    if (cn > 0) {
      float e = -1e30f;
      if (h < cn) e = leaky02(s_as[(myb + e0 + h) & (CAPE - 1)] + adn);
      float cm = e;
      #pragma unroll
      for (int ofs = 32; ofs > 0; ofs >>= 1) cm = fmaxf(cm, __shfl_xor(cm, ofs));
      float mn = fmaxf(m, cm);
      float w = (h < cn) ? __expf(e - mn) : 0.f;
      float ds = w;
      #pragma unroll
      for (int ofs = 32; ofs > 0; ofs >>= 1) ds += __shfl_xor(ds, ofs);
      float sc = __expf(m - mn);
      den = den * sc + ds;
      S *= sc;
      m = mn;
      for (int j = 0; j < cn; j++) {
        float wj = __shfl(w, j);
        int pkj = s_pk[(myb + e0 + j) & (CAPE - 1)];
        int tj = pkj >> 20;
        int slot = wid * RPN + j;
        float xp = bf2f(s_rows[slot][0][h]);
        float xr = bf2f(s_rows[slot][1][h]);
        S += wj * xp;
        float gt = tj == 0 ? g0 : (tj == 1 ? g1 : g2);
        float bt = tj == 0 ? b0 : (tj == 1 ? b1 : b2);
        float msg = fmaxf(gt * xr + bt, 0.f);
        if (tj == 0)      { f0 += msg; c0++; }
        else if (tj == 1) { f1 += msg; c1++; }
        else              { f2 += msg; c2++; }
      }
    }
    __syncthreads();
  }

  float agg = f0 / (float)(c0 > 1 ? c0 : 1)
            + f1 / (float)(c1 > 1 ? c1 : 1)
            + f2 / (float)(c2 > 1 ? c2 : 1);
  float o1 = fmaxf(S0[(size_t)n * 64 + h] + agg, 0.f);
  float o2 = fmaxf(S / den + gat_b[h], 0.f);
  F[(size_t)n * 128 + h]      = o1;
  F[(size_t)n * 128 + 64 + h] = o2;
  if (h == 0) {
    int g = gb[n];
    if (n == 0 || gb[n - 1] != g)      gstart[g] = n;
    if (n == NN - 1 || gb[n + 1] != g) gend[g] = n;
  }
}

// ---- parallel pooling: 8 chunks per graph, atomic max/sum ---------------
__global__ __launch_bounds__(128) void pool_k(const float* __restrict__ F,
    const int* __restrict__ gstart, const int* __restrict__ gend,
    float* __restrict__ pmax, float* __restrict__ psum) {
  int g = blockIdx.x, chunk = blockIdx.y, f = threadIdx.x;
  int s = gstart[g], e = gend[g];
  if (s > e || s >= NN || s < 0) return;
  if (e >= NN) e = NN - 1;
  int len = e - s + 1;
  int per = (len + 7) >> 3;
  int a = s + chunk * per;
  int bnd = a + per; if (bnd > e + 1) bnd = e + 1;
  if (a >= bnd) return;
  float mx = 0.f, sm = 0.f;          // feats >= 0 (both relu'd)
  for (int n = a; n < bnd; n++) {
    float v = F[(size_t)n * 128 + f];
    mx = fmaxf(mx, v);
    sm += v;
  }
  atomicMaxFPos(&pmax[g * 128 + f], mx);
  atomicAdd(&psum[g * 128 + f], sm);
}

// ---- head MLP + log_softmax (fp32 out) ----------------------------------
__global__ __launch_bounds__(64) void head_k(const float* __restrict__ pmax,
    const float* __restrict__ psum, const int* __restrict__ gstart,
    const int* __restrict__ gend,
    const float* __restrict__ lin_W, const float* __restrict__ lin_b,
    const float* __restrict__ fc_W, const float* __restrict__ fc_b,
    float* __restrict__ out) {
  __shared__ float p[256];
  __shared__ float hid[64];
  __shared__ float lg[CC];
  __shared__ float lse;
  int g = blockIdx.x, t = threadIdx.x;
  int s = gstart[g], e = gend[g];
  int cnt = (s <= e && s < NN && s >= 0) ? (e - s + 1) : 0;
  float invc = 1.f / (float)(cnt > 1 ? cnt : 1);
  for (int i = t; i < 256; i += 64)
    p[i] = (i < 128) ? pmax[g * 128 + i] : psum[g * 128 + (i - 128)] * invc;
  __syncthreads();
  float acc = lin_b[t];
  for (int k = 0; k < 256; k++) acc += p[k] * lin_W[k * 64 + t];
  hid[t] = fmaxf(acc, 0.f);
  __syncthreads();
  if (t < CC) {
    float a = fc_b[t];
    for (int k = 0; k < 64; k++) a += hid[k] * fc_W[k * CC + t];
    lg[t] = a;
  }
  __syncthreads();
  if (t == 0) {
    float mx = lg[0];
    for (int i = 1; i < CC; i++) mx = fmaxf(mx, lg[i]);
    float sum = 0.f;
    for (int i = 0; i < CC; i++) sum += expf(lg[i] - mx);
    lse = mx + logf(sum);
  }
  __syncthreads();
  if (t < CC) out[g * CC + t] = lg[t] - lse;
}

extern "C" void kernel_launch(void* const* d_in, const int* in_sizes, int n_in,
                              void* d_out, int out_size, void* d_ws, size_t ws_size,
                              hipStream_t stream) {
  const float* x            = (const float*)d_in[0];
  const int*   edge_index   = (const int*)d_in[1];
  const int*   edge_type    = (const int*)d_in[2];
  const int*   graph_batch  = (const int*)d_in[3];
  const float* film_lin_W   = (const float*)d_in[4];
  const float* film_film_W  = (const float*)d_in[5];
  const float* film_film_b  = (const float*)d_in[6];
  const float* skip_W       = (const float*)d_in[7];
  const float* skip_film_W  = (const float*)d_in[8];
  const float* skip_film_b  = (const float*)d_in[9];
  const float* gat_W        = (const float*)d_in[10];
  const float* att_src      = (const float*)d_in[11];
  const float* att_dst      = (const float*)d_in[12];
  const float* gat_b        = (const float*)d_in[13];
  const float* lin_W        = (const float*)d_in[14];
  const float* lin_b        = (const float*)d_in[15];
  const float* fc_W         = (const float*)d_in[16];
  const float* fc_b         = (const float*)d_in[17];
  float* out                = (float*)d_out;

  float* ws = (float*)d_ws;
  const size_t N = NN, E = EE, G = GG;
  size_t oYb     = 0;                       // N*416 fl slots (N*832 bf16)
  size_t oF      = N * 416;                 // N*128 f32
  size_t oS0     = oF + N * 128;            // N*64 f32
  size_t oAs     = oS0 + N * 64;            // N
  size_t oAd     = oAs + N;                 // N
  size_t oXbf    = oAd + N;                 // N*32 fl slots (N*64 shorts)
  size_t oWt     = oXbf + N * 32;           // 832*32 fl slots
  size_t oBias   = oWt + 832 * 32;          // 832
  size_t oPmax   = oBias + 832;             // G*128 } zero region
  size_t oPsum   = oPmax + G * 128;         // G*128 }
  size_t oGend   = oPsum + G * 128;         // G     }
  size_t oDeg    = oGend + G;               // N     }
  size_t oFill   = oDeg + N;                // N     }
  size_t oGstart = oFill + N;               // G (0x7f)
  size_t oOff    = oGstart + G;             // N+1
  size_t oTsum   = oOff + N + 1;            // 256
  size_t oTbase  = oTsum + 256;             // 256
  size_t oSorted = oTbase + 256;            // E

  unsigned short* Yb  = (unsigned short*)(ws + oYb);
  float* F      = ws + oF;
  float* S0     = ws + oS0;
  float* as_    = ws + oAs;
  float* ad_    = ws + oAd;
  unsigned short* Xbf = (unsigned short*)(ws + oXbf);
  unsigned short* Wt  = (unsigned short*)(ws + oWt);
  float* bias   = ws + oBias;
  float* pmax   = ws + oPmax;
  float* psum   = ws + oPsum;
  int*   gend   = (int*)(ws + oGend);
  int*   deg    = (int*)(ws + oDeg);
  int*   fill   = (int*)(ws + oFill);
  int*   gstart = (int*)(ws + oGstart);
  int*   off    = (int*)(ws + oOff);
  int*   tsum   = (int*)(ws + oTsum);
  int*   tbase  = (int*)(ws + oTbase);
  int*   sorted = (int*)(ws + oSorted);

  size_t zeroFloats = oGstart - oPmax;   // pmax,psum,gend,deg,fill
  hipMemsetAsync(pmax, 0, zeroFloats * sizeof(float), stream);
  hipMemsetAsync(gstart, 0x7f, G * sizeof(int), stream);

  prep_k<<<3125 + 210, 256, 0, stream>>>(x, Xbf, edge_index, deg,
      skip_film_W, skip_W, film_lin_W, film_film_W, gat_W,
      skip_film_b, film_film_b, Wt, bias);
  gemm_k<<<dim3((NN + 63) / 64, 7), 256, 0, stream>>>(Xbf, Wt, bias, Yb);
  post_k<<<(NN + 3) / 4, 256, 0, stream>>>(Yb, att_src, att_dst, as_, ad_, S0);
  scanA_k<<<NT, 256, 0, stream>>>(deg, off, tsum);
  scanB_k<<<1, 256, 0, stream>>>(tsum, tbase, off);
  scanC_k<<<NT, 256, 0, stream>>>(off, tbase);
  scatter_k<<<(EE + 255) / 256, 256, 0, stream>>>(edge_index, edge_type,
                                                  off, fill, sorted);
  dst_k<<<NN / 4, 256, 0, stream>>>(sorted, off, Yb, S0, as_, ad_,
                                    gat_b, graph_batch, F, gstart, gend);
  pool_k<<<dim3(GG, 8), 128, 0, stream>>>(F, gstart, gend, pmax, psum);
  head_k<<<GG, 64, 0, stream>>>(pmax, psum, gstart, gend,
                                lin_W, lin_b, fc_W, fc_b, out);
}

// Round 12
// 323.752 us; speedup vs baseline: 2.8045x; 1.0541x over previous
//
#include <hip/hip_runtime.h>
#include <hip/hip_bf16.h>

// Problem constants (from reference)
#define NN 50000
#define EE 800000
#define GG 64
#define RR 3
#define CC 10
// Yb bf16 per node (832 cols): [0:192 UNUSED | 192:384 xr(r=0..2) |
//                               384:768 fm(r, beta|gamma) | 768:832 xp]
// gemm_k: full-row MFMA GEMM (7 B-tiles looped in-kernel), post FUSED:
// fs/xs tiles stay in registers (never stored); skip_out->S0, att scalars
// computed in-register from C-fragments. dst_k: gathers Yb rows, feats ->
// F[n][128] f32; graph boundaries by sorted-gb neighbor compare
// (NO atomics: 64-addr atomicMin/Max serialized ~350us, rounds 3-7).

typedef __attribute__((ext_vector_type(8))) short bf16x8;
typedef __attribute__((ext_vector_type(4))) float f32x4;

__device__ inline float leaky02(float x) { return x > 0.f ? x : 0.2f * x; }

// valid for non-negative floats only (int compare == float compare there)
__device__ inline void atomicMaxFPos(float* addr, float v) {
  atomicMax((int*)addr, __float_as_int(v));
}

__device__ inline unsigned short f2bf(float f) {
  __hip_bfloat16 b = __float2bfloat16(f);
  return *reinterpret_cast<unsigned short*>(&b);
}
__device__ inline float bf2f(unsigned short u) {
  return __uint_as_float(((unsigned int)u) << 16);   // exact widening
}

// ---- fused prep: X->bf16 + deg count (blocks 0..3124), W pack (rest) ----
__global__ void prep_k(const float* __restrict__ X,
                       unsigned short* __restrict__ Xbf,
                       const int* __restrict__ ei, int* __restrict__ deg,
                       const float* __restrict__ skip_film_W,
                       const float* __restrict__ skip_W,
                       const float* __restrict__ film_lin_W,
                       const float* __restrict__ film_film_W,
                       const float* __restrict__ gat_W,
                       const float* __restrict__ skip_film_b,
                       const float* __restrict__ film_film_b,
                       unsigned short* __restrict__ Wt,
                       float* __restrict__ bias) {
  int b = blockIdx.x;
  if (b < 3125) {
    int i = b * 256 + threadIdx.x;         // < 800000
    int idx = i * 4;
    float4 v = *reinterpret_cast<const float4*>(X + idx);
    ushort4 o = {f2bf(v.x), f2bf(v.y), f2bf(v.z), f2bf(v.w)};
    *reinterpret_cast<ushort4*>(Xbf + idx) = o;
    atomicAdd(&deg[ei[EE + i]], 1);
    return;
  }
  int idx = (b - 3125) * 256 + threadIdx.x;
  if (idx >= 832 * 64 + 832) return;
  if (idx >= 832 * 64) {
    int c = idx - 832 * 64;
    float bv = 0.f;
    if (c < 128) bv = skip_film_b[c];
    else if (c >= 384 && c < 768) bv = film_film_b[c - 384];
    bias[c] = bv;
    return;
  }
  int c = idx >> 6, k = idx & 63;      // Wt[c][k] = Wcat[k][c]
  float v;
  if (c < 128)      v = skip_film_W[k * 128 + c];
  else if (c < 192) v = skip_W[k * 64 + (c - 128)];
  else if (c < 384) { int cc = c - 192, r = cc >> 6, h = cc & 63;
                      v = film_lin_W[(r * 64 + k) * 64 + h]; }
  else if (c < 768) { int cc = c - 384, r = cc >> 7, j = cc & 127;
                      v = film_film_W[(r * 64 + k) * 128 + j]; }
  else              v = gat_W[k * 64 + (c - 768)];
  Wt[idx] = f2bf(v);
}

// ---- full-row MFMA GEMM + fused post ------------------------------------
// Block = 64 rows x all 832 cols (7 B-tiles looped). Tiles: 0 = fs(regs),
// 1 = xs(regs,ct<4) + cols192..255(store), 2..5 = store, 6 = xp(store+regs).
__global__ __launch_bounds__(256) void gemm_k(const unsigned short* __restrict__ Xbf,
    const unsigned short* __restrict__ Wt, const float* __restrict__ bias,
    const float* __restrict__ att_src, const float* __restrict__ att_dst,
    unsigned short* __restrict__ Yb, float* __restrict__ S0,
    float* __restrict__ as_, float* __restrict__ ad_) {
  __shared__ __align__(16) unsigned short As[64][72];
  __shared__ __align__(16) unsigned short Bs[128][72];
  __shared__ __align__(16) unsigned short Cs[4][16][132];
  const int tid = threadIdx.x;
  const int row0 = blockIdx.x * 64;

  // A: 16 shorts/thread (2x uint4), loaded ONCE
  {
    int r = tid >> 2, c0 = (tid & 3) * 16;
    int gr = row0 + r;
    uint4 v0 = {0, 0, 0, 0}, v1 = {0, 0, 0, 0};
    if (gr < NN) {
      const uint4* p = reinterpret_cast<const uint4*>(Xbf + (size_t)gr * 64 + c0);
      v0 = p[0]; v1 = p[1];
    }
    *reinterpret_cast<uint4*>(&As[r][c0])     = v0;
    *reinterpret_cast<uint4*>(&As[r][c0 + 8]) = v1;
  }
  __syncthreads();

  const int w = tid >> 6, lane = tid & 63;
  const int m = lane & 15, q = lane >> 4;
  bf16x8 a0 = *reinterpret_cast<const bf16x8*>(&As[16 * w + m][q * 8]);
  bf16x8 a1 = *reinterpret_cast<const bf16x8*>(&As[16 * w + m][32 + q * 8]);

  f32x4 t0[8], t1[4], t6[4];           // fs, xs, xp fragments kept in regs

  for (int tile = 0; tile < 7; tile++) {
    __syncthreads();                   // all waves done with previous Bs
    int col0 = tile * 128;
    int width = (tile == 6) ? 64 : 128;
    {
      int c = tid >> 1, half = (tid & 1) * 32;
      if (c < width) {
        int gc = col0 + c;
        const uint4* p = reinterpret_cast<const uint4*>(Wt + (size_t)gc * 64 + half);
        uint4 v0 = p[0], v1 = p[1], v2 = p[2], v3 = p[3];
        *reinterpret_cast<uint4*>(&Bs[c][half])      = v0;
        *reinterpret_cast<uint4*>(&Bs[c][half + 8])  = v1;
        *reinterpret_cast<uint4*>(&Bs[c][half + 16]) = v2;
        *reinterpret_cast<uint4*>(&Bs[c][half + 24]) = v3;
      }
    }
    __syncthreads();
    #pragma unroll
    for (int ct = 0; ct < 8; ct++) {
      if (tile == 6 && ct >= 4) continue;
      bf16x8 b0 = *reinterpret_cast<const bf16x8*>(&Bs[ct * 16 + m][q * 8]);
      bf16x8 b1 = *reinterpret_cast<const bf16x8*>(&Bs[ct * 16 + m][32 + q * 8]);
      f32x4 acc = {0.f, 0.f, 0.f, 0.f};
      acc = __builtin_amdgcn_mfma_f32_16x16x32_bf16(a0, b0, acc, 0, 0, 0);
      acc = __builtin_amdgcn_mfma_f32_16x16x32_bf16(a1, b1, acc, 0, 0, 0);
      if (tile == 0) { t0[ct] = acc; continue; }
      if (tile == 1 && ct < 4) { t1[ct] = acc; continue; }
      if (tile == 6) t6[ct] = acc;
      int gc = col0 + ct * 16 + m;
      float bv = bias[gc];
      #pragma unroll
      for (int rg = 0; rg < 4; rg++)
        Cs[w][q * 4 + rg][ct * 16 + m] = f2bf(acc[rg] + bv);
    }
    // wave-synchronous store-out (Cs[w] private to wave)
    if (tile >= 2 && tile <= 5) {      // 128-col store
      int halfrow = lane >> 5;
      int c4 = (lane & 31) * 4;
      #pragma unroll
      for (int step = 0; step < 8; step++) {
        int lr = step * 2 + halfrow;
        int gr = row0 + w * 16 + lr;
        if (gr < NN) {
          uint2 v = *reinterpret_cast<const uint2*>(&Cs[w][lr][c4]);
          *reinterpret_cast<uint2*>(&Yb[(size_t)gr * 832 + col0 + c4]) = v;
        }
      }
    } else if (tile == 1 || tile == 6) {  // 64-col store
      int srcoff = (tile == 1) ? 64 : 0;
      int dstcol = (tile == 1) ? 192 : 768;
      int halfrow = lane >> 5;
      int c2 = (lane & 31) * 2;
      #pragma unroll
      for (int step = 0; step < 8; step++) {
        int lr = step * 2 + halfrow;
        int gr = row0 + w * 16 + lr;
        if (gr < NN) {
          unsigned int v = *reinterpret_cast<const unsigned int*>(&Cs[w][lr][srcoff + c2]);
          *reinterpret_cast<unsigned int*>(&Yb[(size_t)gr * 832 + dstcol + c2]) = v;
        }
      }
    }
  }

  // ---- fused post: all in-lane (same m, same q/reg across tiles) ----
  float pa[4] = {0.f, 0.f, 0.f, 0.f}, pd[4] = {0.f, 0.f, 0.f, 0.f};
  #pragma unroll
  for (int j = 0; j < 4; j++) {
    int h = 16 * j + m;
    float bb = bias[h];
    float bg = bias[64 + h];
    float asv = att_src[h];
    float adv = att_dst[h];
    #pragma unroll
    for (int rg = 0; rg < 4; rg++) {
      float so = fmaxf((t0[4 + j][rg] + bg) * t1[j][rg] + (t0[j][rg] + bb), 0.f);
      int gr = row0 + 16 * w + q * 4 + rg;
      if (gr < NN) S0[(size_t)gr * 64 + h] = so;
      pa[rg] += t6[j][rg] * asv;
      pd[rg] += t6[j][rg] * adv;
    }
  }
  #pragma unroll
  for (int ofs = 1; ofs < 16; ofs <<= 1) {
    #pragma unroll
    for (int rg = 0; rg < 4; rg++) {
      pa[rg] += __shfl_xor(pa[rg], ofs);
      pd[rg] += __shfl_xor(pd[rg], ofs);
    }
  }
  if (m == 0) {
    #pragma unroll
    for (int rg = 0; rg < 4; rg++) {
      int gr = row0 + 16 * w + q * 4 + rg;
      if (gr < NN) { as_[gr] = pa[rg]; ad_[gr] = pd[rg]; }
    }
  }
}

// ---- 3-phase parallel exclusive scan ------------------------------------
#define NT 196   // ceil(50000/256)
__global__ __launch_bounds__(256) void scanA_k(const int* __restrict__ deg,
    int* __restrict__ off, int* __restrict__ tsum) {
  __shared__ int s[256];
  int t = threadIdx.x, idx = blockIdx.x * 256 + t;
  int v = (idx < NN) ? deg[idx] : 0;
  s[t] = v;
  __syncthreads();
  for (int ofs = 1; ofs < 256; ofs <<= 1) {
    int u = (t >= ofs) ? s[t - ofs] : 0;
    __syncthreads();
    s[t] += u;
    __syncthreads();
  }
  if (idx < NN) off[idx] = s[t] - v;
  if (t == 255) tsum[blockIdx.x] = s[255];
}

__global__ __launch_bounds__(256) void scanB_k(const int* __restrict__ tsum,
    int* __restrict__ tbase, int* __restrict__ off) {
  __shared__ int s[256];
  int t = threadIdx.x;
  int v = (t < NT) ? tsum[t] : 0;
  s[t] = v;
  __syncthreads();
  for (int ofs = 1; ofs < 256; ofs <<= 1) {
    int u = (t >= ofs) ? s[t - ofs] : 0;
    __syncthreads();
    s[t] += u;
    __syncthreads();
  }
  if (t < NT) tbase[t] = s[t] - v;
  if (t == 255) off[NN] = s[255];
}

__global__ __launch_bounds__(256) void scanC_k(int* __restrict__ off,
    const int* __restrict__ tbase) {
  int idx = blockIdx.x * 256 + threadIdx.x;
  if (idx < NN) off[idx] += tbase[blockIdx.x];
}

// ---- CSR build: scatter (src|type packed) -------------------------------
__global__ void scatter_k(const int* __restrict__ ei, const int* __restrict__ et,
                          const int* __restrict__ off, int* __restrict__ fill,
                          int* __restrict__ sorted) {
  int e = blockIdx.x * blockDim.x + threadIdx.x;
  if (e >= EE) return;
  int src = ei[e], dst = ei[EE + e], t = et[e];
  int pos = off[dst] + atomicAdd(&fill[dst], 1);
  sorted[pos] = src | (t << 20);
}

// ---- fused per-dst with cooperative block-level gather into LDS ----------
#define RPN 16    // edges per node per round
#define CAPE 256  // max edges per block window

__global__ __launch_bounds__(256) void dst_k(const int* __restrict__ sorted,
    const int* __restrict__ off, const unsigned short* __restrict__ Yb,
    const float* __restrict__ S0,
    const float* __restrict__ as_, const float* __restrict__ ad_,
    const float* __restrict__ gat_b, const int* __restrict__ gb,
    float* __restrict__ F, int* __restrict__ gstart, int* __restrict__ gend) {
  __shared__ int   s_pk[CAPE];
  __shared__ float s_as[CAPE];
  __shared__ __align__(16) unsigned short s_rows[64][2][64];  // 16 KB
  __shared__ int s_b[4], s_deg[4];

  int tid = threadIdx.x;
  int wid = tid >> 6, h = tid & 63;
  int n0 = blockIdx.x * 4;
  int n = n0 + wid;                      // always < NN (50000 = 12500*4)

  int o0 = off[n0];
  int T = off[n0 + 4] - o0; if (T > CAPE) T = CAPE;

  if (tid < T) {
    int pk = sorted[o0 + tid];
    s_pk[tid] = pk;
    int s = pk & 0xFFFFF; if (s >= NN) s = NN - 1;
    s_as[tid] = as_[s];
  }
  if (h == 0) {
    int on = off[n], on1 = off[n + 1];
    int b = on - o0, d = on1 - on;
    if (b > CAPE) b = CAPE;
    if (b + d > CAPE) d = CAPE - b;
    s_b[wid] = b; s_deg[wid] = d;
  }
  __syncthreads();

  int myb = s_b[wid], mydeg = s_deg[wid];
  int dmax = max(max(s_deg[0], s_deg[1]), max(s_deg[2], s_deg[3]));
  int rounds = (dmax + RPN - 1) / RPN;

  const unsigned short* yd = Yb + (size_t)n * 832;
  float b0 = bf2f(yd[384 + h]), g0 = bf2f(yd[448 + h]);
  float b1 = bf2f(yd[512 + h]), g1 = bf2f(yd[576 + h]);
  float b2 = bf2f(yd[640 + h]), g2 = bf2f(yd[704 + h]);
  float adn = ad_[n];
  float m = leaky02(as_[n] + adn);
  float den = 1.f;
  float S = bf2f(yd[768 + h]);         // self xp
  float f0 = 0.f, f1 = 0.f, f2 = 0.f;
  int c0 = 0, c1 = 0, c2 = 0;

  const int grp = tid >> 3, lane8 = tid & 7;

  for (int r = 0; r < rounds; r++) {
    int e0 = r * RPN;
    #pragma unroll
    for (int k = 0; k < 4; k++) {
      int ri = grp + 32 * k;
      int slot = ri & 63;
      int part = ri >> 6;               // 0 = xp(col768), 1 = xr_t(col192+64t)
      int wd = slot >> 4, j = slot & 15;
      int jj = e0 + j;
      if (jj < s_deg[wd]) {
        int be = (s_b[wd] + jj) & (CAPE - 1);
        int pk = s_pk[be];
        int src = pk & 0xFFFFF; if (src >= NN) src = NN - 1;
        int t = pk >> 20;
        const unsigned short* row = Yb + (size_t)src * 832
                                  + (part ? (192 + (t << 6)) : 768);
        uint4 v = *reinterpret_cast<const uint4*>(row + lane8 * 8);
        *reinterpret_cast<uint4*>(&s_rows[slot][part][lane8 * 8]) = v;
      }
    }
    __syncthreads();
    int cn = mydeg - e0; if (cn > RPN) cn = RPN;
    if (cn > 0) {
      float e = -1e30f;
      if (h < cn) e = leaky02(s_as[(myb + e0 + h) & (CAPE - 1)] + adn);
      float cm = e;
      #pragma unroll
      for (int ofs = 32; ofs > 0; ofs >>= 1) cm = fmaxf(cm, __shfl_xor(cm, ofs));
      float mn = fmaxf(m, cm);
      float w = (h < cn) ? __expf(e - mn) : 0.f;
      float ds = w;
      #pragma unroll
      for (int ofs = 32; ofs > 0; ofs >>= 1) ds += __shfl_xor(ds, ofs);
      float sc = __expf(m - mn);
      den = den * sc + ds;
      S *= sc;
      m = mn;
      for (int j = 0; j < cn; j++) {
        float wj = __shfl(w, j);
        int pkj = s_pk[(myb + e0 + j) & (CAPE - 1)];
        int tj = pkj >> 20;
        int slot = wid * RPN + j;
        float xp = bf2f(s_rows[slot][0][h]);
        float xr = bf2f(s_rows[slot][1][h]);
        S += wj * xp;
        float gt = tj == 0 ? g0 : (tj == 1 ? g1 : g2);
        float bt = tj == 0 ? b0 : (tj == 1 ? b1 : b2);
        float msg = fmaxf(gt * xr + bt, 0.f);
        if (tj == 0)      { f0 += msg; c0++; }
        else if (tj == 1) { f1 += msg; c1++; }
        else              { f2 += msg; c2++; }
      }
    }
    __syncthreads();
  }

  float agg = f0 / (float)(c0 > 1 ? c0 : 1)
            + f1 / (float)(c1 > 1 ? c1 : 1)
            + f2 / (float)(c2 > 1 ? c2 : 1);
  float o1 = fmaxf(S0[(size_t)n * 64 + h] + agg, 0.f);
  float o2 = fmaxf(S / den + gat_b[h], 0.f);
  F[(size_t)n * 128 + h]      = o1;
  F[(size_t)n * 128 + 64 + h] = o2;
  if (h == 0) {
    int g = gb[n];
    if (n == 0 || gb[n - 1] != g)      gstart[g] = n;
    if (n == NN - 1 || gb[n + 1] != g) gend[g] = n;
  }
}

// ---- parallel pooling: 8 chunks per graph, atomic max/sum ---------------
__global__ __launch_bounds__(128) void pool_k(const float* __restrict__ F,
    const int* __restrict__ gstart, const int* __restrict__ gend,
    float* __restrict__ pmax, float* __restrict__ psum) {
  int g = blockIdx.x, chunk = blockIdx.y, f = threadIdx.x;
  int s = gstart[g], e = gend[g];
  if (s > e || s >= NN || s < 0) return;
  if (e >= NN) e = NN - 1;
  int len = e - s + 1;
  int per = (len + 7) >> 3;
  int a = s + chunk * per;
  int bnd = a + per; if (bnd > e + 1) bnd = e + 1;
  if (a >= bnd) return;
  float mx = 0.f, sm = 0.f;          // feats >= 0 (both relu'd)
  for (int n = a; n < bnd; n++) {
    float v = F[(size_t)n * 128 + f];
    mx = fmaxf(mx, v);
    sm += v;
  }
  atomicMaxFPos(&pmax[g * 128 + f], mx);
  atomicAdd(&psum[g * 128 + f], sm);
}

// ---- head MLP + log_softmax (fp32 out) ----------------------------------
__global__ __launch_bounds__(64) void head_k(const float* __restrict__ pmax,
    const float* __restrict__ psum, const int* __restrict__ gstart,
    const int* __restrict__ gend,
    const float* __restrict__ lin_W, const float* __restrict__ lin_b,
    const float* __restrict__ fc_W, const float* __restrict__ fc_b,
    float* __restrict__ out) {
  __shared__ float p[256];
  __shared__ float hid[64];
  __shared__ float lg[CC];
  __shared__ float lse;
  int g = blockIdx.x, t = threadIdx.x;
  int s = gstart[g], e = gend[g];
  int cnt = (s <= e && s < NN && s >= 0) ? (e - s + 1) : 0;
  float invc = 1.f / (float)(cnt > 1 ? cnt : 1);
  for (int i = t; i < 256; i += 64)
    p[i] = (i < 128) ? pmax[g * 128 + i] : psum[g * 128 + (i - 128)] * invc;
  __syncthreads();
  float acc = lin_b[t];
  for (int k = 0; k < 256; k++) acc += p[k] * lin_W[k * 64 + t];
  hid[t] = fmaxf(acc, 0.f);
  __syncthreads();
  if (t < CC) {
    float a = fc_b[t];
    for (int k = 0; k < 64; k++) a += hid[k] * fc_W[k * CC + t];
    lg[t] = a;
  }
  __syncthreads();
  if (t == 0) {
    float mx = lg[0];
    for (int i = 1; i < CC; i++) mx = fmaxf(mx, lg[i]);
    float sum = 0.f;
    for (int i = 0; i < CC; i++) sum += expf(lg[i] - mx);
    lse = mx + logf(sum);
  }
  __syncthreads();
  if (t < CC) out[g * CC + t] = lg[t] - lse;
}

extern "C" void kernel_launch(void* const* d_in, const int* in_sizes, int n_in,
                              void* d_out, int out_size, void* d_ws, size_t ws_size,
                              hipStream_t stream) {
  const float* x            = (const float*)d_in[0];
  const int*   edge_index   = (const int*)d_in[1];
  const int*   edge_type    = (const int*)d_in[2];
  const int*   graph_batch  = (const int*)d_in[3];
  const float* film_lin_W   = (const float*)d_in[4];
  const float* film_film_W  = (const float*)d_in[5];
  const float* film_film_b  = (const float*)d_in[6];
  const float* skip_W       = (const float*)d_in[7];
  const float* skip_film_W  = (const float*)d_in[8];
  const float* skip_film_b  = (const float*)d_in[9];
  const float* gat_W        = (const float*)d_in[10];
  const float* att_src      = (const float*)d_in[11];
  const float* att_dst      = (const float*)d_in[12];
  const float* gat_b        = (const float*)d_in[13];
  const float* lin_W        = (const float*)d_in[14];
  const float* lin_b        = (const float*)d_in[15];
  const float* fc_W         = (const float*)d_in[16];
  const float* fc_b         = (const float*)d_in[17];
  float* out                = (float*)d_out;

  float* ws = (float*)d_ws;
  const size_t N = NN, E = EE, G = GG;
  size_t oYb     = 0;                       // N*416 fl slots (N*832 bf16)
  size_t oF      = N * 416;                 // N*128 f32
  size_t oS0     = oF + N * 128;            // N*64 f32
  size_t oAs     = oS0 + N * 64;            // N
  size_t oAd     = oAs + N;                 // N
  size_t oXbf    = oAd + N;                 // N*32 fl slots (N*64 shorts)
  size_t oWt     = oXbf + N * 32;           // 832*32 fl slots
  size_t oBias   = oWt + 832 * 32;          // 832
  size_t oPmax   = oBias + 832;             // G*128 } zero region
  size_t oPsum   = oPmax + G * 128;         // G*128 }
  size_t oGend   = oPsum + G * 128;         // G     }
  size_t oDeg    = oGend + G;               // N     }
  size_t oFill   = oDeg + N;                // N     }
  size_t oGstart = oFill + N;               // G (0x7f)
  size_t oOff    = oGstart + G;             // N+1
  size_t oTsum   = oOff + N + 1;            // 256
  size_t oTbase  = oTsum + 256;             // 256
  size_t oSorted = oTbase + 256;            // E

  unsigned short* Yb  = (unsigned short*)(ws + oYb);
  float* F      = ws + oF;
  float* S0     = ws + oS0;
  float* as_    = ws + oAs;
  float* ad_    = ws + oAd;
  unsigned short* Xbf = (unsigned short*)(ws + oXbf);
  unsigned short* Wt  = (unsigned short*)(ws + oWt);
  float* bias   = ws + oBias;
  float* pmax   = ws + oPmax;
  float* psum   = ws + oPsum;
  int*   gend   = (int*)(ws + oGend);
  int*   deg    = (int*)(ws + oDeg);
  int*   fill   = (int*)(ws + oFill);
  int*   gstart = (int*)(ws + oGstart);
  int*   off    = (int*)(ws + oOff);
  int*   tsum   = (int*)(ws + oTsum);
  int*   tbase  = (int*)(ws + oTbase);
  int*   sorted = (int*)(ws + oSorted);

  size_t zeroFloats = oGstart - oPmax;   // pmax,psum,gend,deg,fill
  hipMemsetAsync(pmax, 0, zeroFloats * sizeof(float), stream);
  hipMemsetAsync(gstart, 0x7f, G * sizeof(int), stream);

  prep_k<<<3125 + 210, 256, 0, stream>>>(x, Xbf, edge_index, deg,
      skip_film_W, skip_W, film_lin_W, film_film_W, gat_W,
      skip_film_b, film_film_b, Wt, bias);
  gemm_k<<<(NN + 63) / 64, 256, 0, stream>>>(Xbf, Wt, bias, att_src, att_dst,
                                             Yb, S0, as_, ad_);
  scanA_k<<<NT, 256, 0, stream>>>(deg, off, tsum);
  scanB_k<<<1, 256, 0, stream>>>(tsum, tbase, off);
  scanC_k<<<NT, 256, 0, stream>>>(off, tbase);
  scatter_k<<<(EE + 255) / 256, 256, 0, stream>>>(edge_index, edge_type,
                                                  off, fill, sorted);
  dst_k<<<NN / 4, 256, 0, stream>>>(sorted, off, Yb, S0, as_, ad_,
                                    gat_b, graph_batch, F, gstart, gend);
  pool_k<<<dim3(GG, 8), 128, 0, stream>>>(F, gstart, gend, pmax, psum);
  head_k<<<GG, 64, 0, stream>>>(pmax, psum, gstart, gend,
                                lin_W, lin_b, fc_W, fc_b, out);
}